// Round 2
// baseline (1759.918 us; speedup 1.0000x reference)
//
#include <hip/hip_runtime.h>
#include <math.h>

#define CH 512
#define K 64
#define BB 8
#define NIMG 5
#define HW 1024
#define NP 5120   // NIMG*HW
#define BI 40     // BB*NIMG

// ---------------- conv GEMM (1x1 conv = per-image 512x512 GEMM) -------------
// out[d,p] = sum_c W[d,c] * in[c,p] (+ bias)
// mode 0 (conv1): in = x[bi][c][hw],  out = y[b][d][n*HW + p]
// mode 1 (conv2): in = rec[b][c][n*HW + p], out = y2[bi][d][hw]
__global__ __launch_bounds__(256) void conv_gemm(
    const float* __restrict__ in, const float* __restrict__ W,
    const float* __restrict__ bias, float* __restrict__ out,
    int inStrideC, int outStrideD, int mode)
{
    int bi = blockIdx.z;
    int d0 = blockIdx.y * 64;
    int p0 = blockIdx.x * 64;
    long inBase, outBase;
    if (mode == 0) {
        inBase  = (long)bi * CH * HW;
        outBase = (long)(bi / NIMG) * CH * NP + (long)(bi % NIMG) * HW;
    } else {
        inBase  = (long)(bi / NIMG) * CH * NP + (long)(bi % NIMG) * HW;
        outBase = (long)bi * CH * HW;
    }
    __shared__ float As[64][17];   // [d][c] pad -> no 4-way conflict
    __shared__ float Bs[16][64];   // [c][p]
    int t = threadIdx.x;
    int tx = t & 15, ty = t >> 4;
    float acc[4][4] = {};
    for (int c0 = 0; c0 < CH; c0 += 16) {
        __syncthreads();
        #pragma unroll
        for (int l = t; l < 1024; l += 256) {
            int r = l >> 4, kk = l & 15;
            As[r][kk] = W[(long)(d0 + r) * CH + c0 + kk];
        }
        #pragma unroll
        for (int l = t; l < 1024; l += 256) {
            int kk = l >> 6, col = l & 63;
            Bs[kk][col] = in[inBase + (long)(c0 + kk) * inStrideC + p0 + col];
        }
        __syncthreads();
        #pragma unroll
        for (int kk = 0; kk < 16; ++kk) {
            float a0 = As[ty * 4 + 0][kk];
            float a1 = As[ty * 4 + 1][kk];
            float a2 = As[ty * 4 + 2][kk];
            float a3 = As[ty * 4 + 3][kk];
            float4 bv = *(const float4*)&Bs[kk][tx * 4];
            acc[0][0] += a0 * bv.x; acc[0][1] += a0 * bv.y; acc[0][2] += a0 * bv.z; acc[0][3] += a0 * bv.w;
            acc[1][0] += a1 * bv.x; acc[1][1] += a1 * bv.y; acc[1][2] += a1 * bv.z; acc[1][3] += a1 * bv.w;
            acc[2][0] += a2 * bv.x; acc[2][1] += a2 * bv.y; acc[2][2] += a2 * bv.z; acc[2][3] += a2 * bv.w;
            acc[3][0] += a3 * bv.x; acc[3][1] += a3 * bv.y; acc[3][2] += a3 * bv.z; acc[3][3] += a3 * bv.w;
        }
    }
    #pragma unroll
    for (int i = 0; i < 4; ++i) {
        int d = d0 + ty * 4 + i;
        float bb = bias ? bias[d] : 0.f;
        float4 v = make_float4(acc[i][0] + bb, acc[i][1] + bb, acc[i][2] + bb, acc[i][3] + bb);
        *(float4*)&out[outBase + (long)d * outStrideD + p0 + tx * 4] = v;
    }
}

// ---------------- broadcast mu (1,C,K) -> (B,C,K) ---------------------------
__global__ __launch_bounds__(256) void bcast_mu(const float* __restrict__ mu_in,
                                                float* __restrict__ mu_cur)
{
    int i = blockIdx.x * 256 + threadIdx.x;   // BB*CH*K = 262144
    mu_cur[i] = mu_in[i & (CH * K - 1)];      // CH*K = 32768, power of 2
}

// ---------------- EM stage: scores + softmax(k) + z + zsum ------------------
// S[p,k] = sum_c y[b,c,p]*mu[b,c,k]; z = softmax_k(S); zsum[b,k] += sum_p z
__global__ __launch_bounds__(256) void stage_z(
    const float* __restrict__ y, const float* __restrict__ mu,
    float* __restrict__ z, float* __restrict__ zsum)
{
    int b = blockIdx.y;
    int p0 = blockIdx.x * 64;
    int t = threadIdx.x;
    int k = t & 63, pg = t >> 6;  // wave pg owns p = p0 + pg*16 .. +15, lane = k
    __shared__ float ys[16][64];
    __shared__ float ms[16][64];
    __shared__ float zpart[4][64];
    float acc[16] = {};
    const float* yb = y + (long)b * CH * NP;
    const float* mb = mu + (long)b * CH * K;
    for (int c0 = 0; c0 < CH; c0 += 16) {
        __syncthreads();
        #pragma unroll
        for (int l = t; l < 1024; l += 256) {
            int cc = l >> 6, col = l & 63;
            ys[cc][col] = yb[(long)(c0 + cc) * NP + p0 + col];
            ms[cc][col] = mb[(long)(c0 + cc) * K + col];
        }
        __syncthreads();
        #pragma unroll
        for (int cc = 0; cc < 16; ++cc) {
            float m = ms[cc][k];
            const float4* yv = (const float4*)&ys[cc][pg * 16];
            #pragma unroll
            for (int q = 0; q < 4; ++q) {
                float4 v = yv[q];
                acc[q * 4 + 0] += v.x * m; acc[q * 4 + 1] += v.y * m;
                acc[q * 4 + 2] += v.z * m; acc[q * 4 + 3] += v.w * m;
            }
        }
    }
    // softmax over k (across the 64 lanes of this wave) for each of 16 p
    float psum = 0.f;
    float* zb = z + (long)b * NP * K;
    #pragma unroll
    for (int i = 0; i < 16; ++i) {
        float m = acc[i];
        for (int off = 32; off; off >>= 1) m = fmaxf(m, __shfl_xor(m, off, 64));
        float e = __expf(acc[i] - m);
        float s = e;
        for (int off = 32; off; off >>= 1) s += __shfl_xor(s, off, 64);
        float zv = e / s;
        psum += zv;
        zb[(long)(p0 + pg * 16 + i) * K + k] = zv;
    }
    zpart[pg][k] = psum;
    __syncthreads();
    if (t < 64) {
        float s = zpart[0][t] + zpart[1][t] + zpart[2][t] + zpart[3][t];
        atomicAdd(&zsum[b * K + t], s);
    }
}

// ---------------- EM stage: mu_acc[b,c,k] += sum_p y[b,c,p]*z[b,p,k] --------
__global__ __launch_bounds__(256) void stage_mu(
    const float* __restrict__ y, const float* __restrict__ z,
    float* __restrict__ mu_acc)
{
    int b = blockIdx.z;
    int c0 = blockIdx.y * 64;
    int pstart = blockIdx.x * 640;
    int t = threadIdx.x;
    int k = t & 63, cg = t >> 6;
    __shared__ float yst[16][68];  // [pp][c_local], padded+aligned
    __shared__ float zs[16][64];   // [pp][k]
    float acc[16] = {};
    const float* yb = y + (long)b * CH * NP;
    const float* zb = z + (long)b * NP * K;
    for (int p0 = pstart; p0 < pstart + 640; p0 += 16) {
        __syncthreads();
        {
            int cl = t >> 2, pq = t & 3;
            float4 v = *(const float4*)&yb[(long)(c0 + cl) * NP + p0 + pq * 4];
            yst[pq * 4 + 0][cl] = v.x; yst[pq * 4 + 1][cl] = v.y;
            yst[pq * 4 + 2][cl] = v.z; yst[pq * 4 + 3][cl] = v.w;
        }
        #pragma unroll
        for (int l = t; l < 1024; l += 256) {
            int pp = l >> 6, kk = l & 63;
            zs[pp][kk] = zb[(long)(p0 + pp) * K + kk];
        }
        __syncthreads();
        #pragma unroll
        for (int pp = 0; pp < 16; ++pp) {
            float zv = zs[pp][k];
            const float4* yv = (const float4*)&yst[pp][cg * 16];
            #pragma unroll
            for (int q = 0; q < 4; ++q) {
                float4 v = yv[q];
                acc[q * 4 + 0] += v.x * zv; acc[q * 4 + 1] += v.y * zv;
                acc[q * 4 + 2] += v.z * zv; acc[q * 4 + 3] += v.w * zv;
            }
        }
    }
    float* ma = mu_acc + (long)b * CH * K + (long)c0 * K;
    #pragma unroll
    for (int i = 0; i < 16; ++i)
        atomicAdd(&ma[(cg * 16 + i) * K + k], acc[i]);
}

// ---------------- mu normalize: mu = macc / (1e-6*d + ||macc||_c) -----------
__global__ __launch_bounds__(256) void mu_norm(const float* __restrict__ acc,
                                               const float* __restrict__ zsum,
                                               float* __restrict__ mu)
{
    int w = blockIdx.x * 4 + (threadIdx.x >> 6);   // 512 waves = 8b x 64k
    int lane = threadIdx.x & 63;
    int b = w >> 6, k = w & 63;
    const float* ab = acc + (long)b * CH * K;
    float s = 0.f;
    for (int c = lane; c < CH; c += 64) { float v = ab[c * K + k]; s += v * v; }
    for (int off = 32; off; off >>= 1) s += __shfl_xor(s, off, 64);
    float d = 1e-6f + zsum[b * K + k];
    float scale = 1.f / (1e-6f * d + sqrtf(s));
    float* mb = mu + (long)b * CH * K;
    for (int c = lane; c < CH; c += 64) mb[c * K + k] = ab[c * K + k] * scale;
}

// ---------------- rec[b,c,p] = relu(sum_k mu[b,c,k] * z[b,p,k]) -------------
__global__ __launch_bounds__(256) void rec_kernel(
    const float* __restrict__ mu, const float* __restrict__ z,
    float* __restrict__ rec)
{
    int b = blockIdx.y;
    int p0 = blockIdx.x * 64;
    int t = threadIdx.x;
    int p = t & 63, cg = t >> 6;
    __shared__ float zs[64][65];   // [p][k]
    __shared__ float mst[64][68];  // [k][c_local]
    const float* zb = z + (long)b * NP * K;
    const float* mb = mu + (long)b * CH * K;
    #pragma unroll
    for (int l = t; l < 1024; l += 256) {   // 64 rows x 16 float4
        int pr = l >> 4, kq = l & 15;
        float4 v = *(const float4*)&zb[(long)(p0 + pr) * K + kq * 4];
        zs[pr][kq * 4 + 0] = v.x; zs[pr][kq * 4 + 1] = v.y;
        zs[pr][kq * 4 + 2] = v.z; zs[pr][kq * 4 + 3] = v.w;
    }
    float* rb = rec + (long)b * CH * NP;
    for (int c0 = 0; c0 < CH; c0 += 64) {
        __syncthreads();
        // load mu[c0+cl][k] for cl in 0..63, ALL k in 0..63 (1024 float4s)
        #pragma unroll
        for (int l = t; l < 1024; l += 256) {
            int cl = l >> 4, kq = l & 15;
            float4 v = *(const float4*)&mb[(long)(c0 + cl) * K + kq * 4];
            mst[kq * 4 + 0][cl] = v.x; mst[kq * 4 + 1][cl] = v.y;
            mst[kq * 4 + 2][cl] = v.z; mst[kq * 4 + 3][cl] = v.w;
        }
        __syncthreads();
        float acc[16] = {};
        #pragma unroll
        for (int kk = 0; kk < 64; ++kk) {
            float zv = zs[p][kk];
            const float4* mv = (const float4*)&mst[kk][cg * 16];
            #pragma unroll
            for (int q = 0; q < 4; ++q) {
                float4 v = mv[q];
                acc[q * 4 + 0] += v.x * zv; acc[q * 4 + 1] += v.y * zv;
                acc[q * 4 + 2] += v.z * zv; acc[q * 4 + 3] += v.w * zv;
            }
        }
        #pragma unroll
        for (int i = 0; i < 16; ++i)
            rb[(long)(c0 + cg * 16 + i) * NP + p0 + p] = fmaxf(acc[i], 0.f);
    }
}

// ---------------- BN batch stats: one block per channel ---------------------
__global__ __launch_bounds__(256) void bn_stats(const float* __restrict__ y2,
                                                float* __restrict__ stats,
                                                float* __restrict__ statsq)
{
    int d = blockIdx.x;
    int t = threadIdx.x;
    float s = 0.f, sq = 0.f;
    for (int idx = t; idx < BI * HW; idx += 256) {
        int bi = idx >> 10, hw = idx & 1023;
        float v = y2[(long)bi * CH * HW + (long)d * HW + hw];
        s += v; sq += v * v;
    }
    for (int off = 32; off; off >>= 1) {
        s += __shfl_xor(s, off, 64);
        sq += __shfl_xor(sq, off, 64);
    }
    __shared__ float ps[8];
    int wv = t >> 6, ln = t & 63;
    if (ln == 0) { ps[wv] = s; ps[4 + wv] = sq; }
    __syncthreads();
    if (t == 0) {
        stats[d]  = ps[0] + ps[1] + ps[2] + ps[3];
        statsq[d] = ps[4] + ps[5] + ps[6] + ps[7];
    }
}

// ---------------- finale: BN + residual + relu, plus mu_b copy --------------
__global__ __launch_bounds__(256) void final_kernel(
    const float* __restrict__ y2, const float* __restrict__ x,
    const float* __restrict__ stats, const float* __restrict__ statsq,
    const float* __restrict__ gamma, const float* __restrict__ beta,
    const float* __restrict__ mu_cur, float* __restrict__ out)
{
    long i = (long)blockIdx.x * 256 + threadIdx.x;
    const long NMAIN = (long)BI * CH * HW;          // 20971520
    if (i < NMAIN) {
        int d = (int)((i >> 10) & (CH - 1));
        float s = stats[d], sq = statsq[d];
        const float inv = 1.f / (float)(BI * HW);
        float mean = s * inv;
        float var = sq * inv - mean * mean;
        float rs = rsqrtf(var + 1e-5f);
        float v = (y2[i] - mean) * rs * gamma[d] + beta[d] + x[i];
        out[i] = fmaxf(v, 0.f);
    } else if (i < NMAIN + (long)BB * CH * K) {
        out[i] = mu_cur[i - NMAIN];
    }
}

extern "C" void kernel_launch(void* const* d_in, const int* in_sizes, int n_in,
                              void* d_out, int out_size, void* d_ws, size_t ws_size,
                              hipStream_t stream) {
    const float* x   = (const float*)d_in[0];
    const float* mu0 = (const float*)d_in[1];
    const float* w1  = (const float*)d_in[2];
    const float* b1  = (const float*)d_in[3];
    const float* w2  = (const float*)d_in[4];
    const float* gm  = (const float*)d_in[5];
    const float* bt  = (const float*)d_in[6];
    float* out = (float*)d_out;

    float* ws = (float*)d_ws;
    float* y      = ws;                         // 20971520 (also holds rec)
    float* zbuf   = ws + 20971520;              // 2621440
    float* mu_cur = ws + 23592960;              // 262144
    float* mu_acc = ws + 23855104;              // 262144
    float* zsum   = ws + 24117248;              // 512
    float* stats  = ws + 24117760;              // 512
    float* statsq = ws + 24118272;              // 512
    float* y2     = out;                        // y2 lives in d_out (in-place finale)

    // conv1 -> y in EM layout [b][c][n*HW+hw]
    conv_gemm<<<dim3(16, 8, 40), 256, 0, stream>>>(x, w1, b1, y, HW, NP, 0);
    // mu broadcast
    bcast_mu<<<1024, 256, 0, stream>>>(mu0, mu_cur);

    for (int s = 0; s < 5; ++s) {
        hipMemsetAsync(zsum, 0, 512 * sizeof(float), stream);
        hipMemsetAsync(mu_acc, 0, 262144 * sizeof(float), stream);
        stage_z<<<dim3(80, 8), 256, 0, stream>>>(y, mu_cur, zbuf, zsum);
        stage_mu<<<dim3(8, 8, 8), 256, 0, stream>>>(y, zbuf, mu_acc);
        mu_norm<<<128, 256, 0, stream>>>(mu_acc, zsum, mu_cur);
    }

    // rec overwrites y (reads only mu_cur, zbuf)
    rec_kernel<<<dim3(80, 8), 256, 0, stream>>>(mu_cur, zbuf, y);
    // conv2 -> y2 (= d_out main region)
    conv_gemm<<<dim3(16, 8, 40), 256, 0, stream>>>(y, w2, nullptr, y2, NP, HW, 1);
    bn_stats<<<512, 256, 0, stream>>>(y2, stats, statsq);
    // finale in-place over d_out + mu tail
    long total = (long)BI * CH * HW + (long)BB * CH * K;
    final_kernel<<<(int)((total + 255) / 256), 256, 0, stream>>>(
        y2, x, stats, statsq, gm, bt, mu_cur, out);
}

// Round 4
// 1489.871 us; speedup vs baseline: 1.1813x; 1.1813x over previous
//
#include <hip/hip_runtime.h>
#include <math.h>

#define CH 512
#define K 64
#define BB 8
#define NIMG 5
#define HW 1024
#define NP 5120   // NIMG*HW
#define BI 40     // BB*NIMG

typedef __attribute__((ext_vector_type(8))) _Float16 f16x8;
typedef __attribute__((ext_vector_type(4))) float f32x4;

// ---------------- W fp32 -> fp16 (row-major copy) ---------------------------
__global__ __launch_bounds__(256) void wconv(const float* __restrict__ w,
                                             _Float16* __restrict__ o)
{
    int i = blockIdx.x * 256 + threadIdx.x;   // 262144
    o[i] = (_Float16)w[i];
}

// ---------------- transpose fp32 [z][512][P] -> fp16 [z][P][512] ------------
__global__ __launch_bounds__(256) void transpose_f16(
    const float* __restrict__ in, _Float16* __restrict__ out, int P)
{
    __shared__ float tile[64][65];
    int t = threadIdx.x;
    int p0 = blockIdx.x * 64, c0 = blockIdx.y * 64;
    long ibase = (long)blockIdx.z * CH * P;
    long obase = (long)blockIdx.z * P * CH;
    int pl = t & 63, chh = t >> 6;
    #pragma unroll
    for (int i = 0; i < 16; ++i)
        tile[chh + i * 4][pl] = in[ibase + (long)(c0 + chh + i * 4) * P + p0 + pl];
    __syncthreads();
    int cc = t & 31, pr = t >> 5;
    #pragma unroll
    for (int i = 0; i < 8; ++i) {
        int p = pr + i * 8;
        _Float16 lo = (_Float16)tile[cc * 2][p];
        _Float16 hi = (_Float16)tile[cc * 2 + 1][p];
        unsigned lob = (unsigned)*(unsigned short*)&lo;
        unsigned hib = (unsigned)*(unsigned short*)&hi;
        *(unsigned*)&out[obase + (long)(p0 + p) * CH + c0 + cc * 2] = lob | (hib << 16);
    }
}

// ---------------- conv via MFMA: out[d,p] = sum_c W[d,c]*inT[p,c] -----------
// A = Wh (fp16 [512][512], d-major); B = inT (fp16 [rows][512], p-major).
// mode 0 (conv1): inT=xT rows bi*HW+hw,      out y[b][d][n*HW+hw] stride NP (+bias)
// mode 1 (conv2): inT=recT rows b*NP+n*HW+hw, out y2[bi][d][hw]   stride HW
__global__ __launch_bounds__(256) void conv_mfma(
    const _Float16* __restrict__ Wh, const _Float16* __restrict__ inT,
    const float* __restrict__ bias, float* __restrict__ out, int mode)
{
    int t = threadIdx.x;
    int lane = t & 63, wv = t >> 6;
    int l15 = lane & 15, l4 = lane >> 4;
    int bi = blockIdx.z;
    int d0 = blockIdx.y * 64 + wv * 16;     // this wave's 16 d-rows
    int pimg = blockIdx.x * 64;             // p-tile within image
    long inRow0, outBase; int outStride;
    if (mode == 0) {
        inRow0 = (long)bi * HW + pimg;
        outBase = (long)(bi / NIMG) * CH * NP + (long)(bi % NIMG) * HW + pimg;
        outStride = NP;
    } else {
        inRow0 = (long)(bi / NIMG) * NP + (long)(bi % NIMG) * HW + pimg;
        outBase = (long)bi * CH * HW + pimg;
        outStride = HW;
    }
    const _Float16* Abase = Wh + (long)(d0 + l15) * CH + l4 * 8;
    const _Float16* B0 = inT + (inRow0 + 0 * 16 + l15) * (long)CH + l4 * 8;
    const _Float16* B1 = inT + (inRow0 + 1 * 16 + l15) * (long)CH + l4 * 8;
    const _Float16* B2 = inT + (inRow0 + 2 * 16 + l15) * (long)CH + l4 * 8;
    const _Float16* B3 = inT + (inRow0 + 3 * 16 + l15) * (long)CH + l4 * 8;

    f32x4 acc0 = {0.f, 0.f, 0.f, 0.f}, acc1 = acc0, acc2 = acc0, acc3 = acc0;
    #pragma unroll
    for (int c0 = 0; c0 < CH; c0 += 32) {
        f16x8 a  = *(const f16x8*)(Abase + c0);
        f16x8 b0 = *(const f16x8*)(B0 + c0);
        f16x8 b1 = *(const f16x8*)(B1 + c0);
        f16x8 b2 = *(const f16x8*)(B2 + c0);
        f16x8 b3 = *(const f16x8*)(B3 + c0);
        acc0 = __builtin_amdgcn_mfma_f32_16x16x32_f16(a, b0, acc0, 0, 0, 0);
        acc1 = __builtin_amdgcn_mfma_f32_16x16x32_f16(a, b1, acc1, 0, 0, 0);
        acc2 = __builtin_amdgcn_mfma_f32_16x16x32_f16(a, b2, acc2, 0, 0, 0);
        acc3 = __builtin_amdgcn_mfma_f32_16x16x32_f16(a, b3, acc3, 0, 0, 0);
    }
    // C/D: col = lane&15 (p within 16-block), row = (lane>>4)*4 + reg (d)
    #pragma unroll
    for (int i = 0; i < 4; ++i) {
        int d = d0 + l4 * 4 + i;
        float bb = bias ? bias[d] : 0.f;
        long rowb = outBase + (long)d * outStride + l15;
        out[rowb + 0]  = acc0[i] + bb;
        out[rowb + 16] = acc1[i] + bb;
        out[rowb + 32] = acc2[i] + bb;
        out[rowb + 48] = acc3[i] + bb;
    }
}

// ---------------- fp32 fallback conv GEMM (used only if ws too small) -------
__global__ __launch_bounds__(256) void conv_gemm(
    const float* __restrict__ in, const float* __restrict__ W,
    const float* __restrict__ bias, float* __restrict__ out,
    int inStrideC, int outStrideD, int mode)
{
    int bi = blockIdx.z;
    int d0 = blockIdx.y * 64;
    int p0 = blockIdx.x * 64;
    long inBase, outBase;
    if (mode == 0) {
        inBase  = (long)bi * CH * HW;
        outBase = (long)(bi / NIMG) * CH * NP + (long)(bi % NIMG) * HW;
    } else {
        inBase  = (long)(bi / NIMG) * CH * NP + (long)(bi % NIMG) * HW;
        outBase = (long)bi * CH * HW;
    }
    __shared__ float As[64][17];
    __shared__ float Bs[16][64];
    int t = threadIdx.x;
    int tx = t & 15, ty = t >> 4;
    float acc[4][4] = {};
    for (int c0 = 0; c0 < CH; c0 += 16) {
        __syncthreads();
        #pragma unroll
        for (int l = t; l < 1024; l += 256) {
            int r = l >> 4, kk = l & 15;
            As[r][kk] = W[(long)(d0 + r) * CH + c0 + kk];
        }
        #pragma unroll
        for (int l = t; l < 1024; l += 256) {
            int kk = l >> 6, col = l & 63;
            Bs[kk][col] = in[inBase + (long)(c0 + kk) * inStrideC + p0 + col];
        }
        __syncthreads();
        #pragma unroll
        for (int kk = 0; kk < 16; ++kk) {
            float a0 = As[ty * 4 + 0][kk];
            float a1 = As[ty * 4 + 1][kk];
            float a2 = As[ty * 4 + 2][kk];
            float a3 = As[ty * 4 + 3][kk];
            float4 bv = *(const float4*)&Bs[kk][tx * 4];
            acc[0][0] += a0 * bv.x; acc[0][1] += a0 * bv.y; acc[0][2] += a0 * bv.z; acc[0][3] += a0 * bv.w;
            acc[1][0] += a1 * bv.x; acc[1][1] += a1 * bv.y; acc[1][2] += a1 * bv.z; acc[1][3] += a1 * bv.w;
            acc[2][0] += a2 * bv.x; acc[2][1] += a2 * bv.y; acc[2][2] += a2 * bv.z; acc[2][3] += a2 * bv.w;
            acc[3][0] += a3 * bv.x; acc[3][1] += a3 * bv.y; acc[3][2] += a3 * bv.z; acc[3][3] += a3 * bv.w;
        }
    }
    #pragma unroll
    for (int i = 0; i < 4; ++i) {
        int d = d0 + ty * 4 + i;
        float bb = bias ? bias[d] : 0.f;
        float4 v = make_float4(acc[i][0] + bb, acc[i][1] + bb, acc[i][2] + bb, acc[i][3] + bb);
        *(float4*)&out[outBase + (long)d * outStrideD + p0 + tx * 4] = v;
    }
}

// ---------------- broadcast mu (1,C,K) -> (B,C,K) ---------------------------
__global__ __launch_bounds__(256) void bcast_mu(const float* __restrict__ mu_in,
                                                float* __restrict__ mu_cur)
{
    int i = blockIdx.x * 256 + threadIdx.x;
    mu_cur[i] = mu_in[i & (CH * K - 1)];
}

// ---------------- EM stage: scores + softmax(k) + z + zsum ------------------
__global__ __launch_bounds__(256) void stage_z(
    const float* __restrict__ y, const float* __restrict__ mu,
    float* __restrict__ z, float* __restrict__ zsum)
{
    int b = blockIdx.y;
    int p0 = blockIdx.x * 64;
    int t = threadIdx.x;
    int k = t & 63, pg = t >> 6;
    __shared__ float ys[16][64];
    __shared__ float ms[16][64];
    __shared__ float zpart[4][64];
    float acc[16] = {};
    const float* yb = y + (long)b * CH * NP;
    const float* mb = mu + (long)b * CH * K;
    for (int c0 = 0; c0 < CH; c0 += 16) {
        __syncthreads();
        #pragma unroll
        for (int l = t; l < 1024; l += 256) {
            int cc = l >> 6, col = l & 63;
            ys[cc][col] = yb[(long)(c0 + cc) * NP + p0 + col];
            ms[cc][col] = mb[(long)(c0 + cc) * K + col];
        }
        __syncthreads();
        #pragma unroll
        for (int cc = 0; cc < 16; ++cc) {
            float m = ms[cc][k];
            const float4* yv = (const float4*)&ys[cc][pg * 16];
            #pragma unroll
            for (int q = 0; q < 4; ++q) {
                float4 v = yv[q];
                acc[q * 4 + 0] += v.x * m; acc[q * 4 + 1] += v.y * m;
                acc[q * 4 + 2] += v.z * m; acc[q * 4 + 3] += v.w * m;
            }
        }
    }
    float psum = 0.f;
    float* zb = z + (long)b * NP * K;
    #pragma unroll
    for (int i = 0; i < 16; ++i) {
        float m = acc[i];
        for (int off = 32; off; off >>= 1) m = fmaxf(m, __shfl_xor(m, off, 64));
        float e = __expf(acc[i] - m);
        float s = e;
        for (int off = 32; off; off >>= 1) s += __shfl_xor(s, off, 64);
        float zv = e / s;
        psum += zv;
        zb[(long)(p0 + pg * 16 + i) * K + k] = zv;
    }
    zpart[pg][k] = psum;
    __syncthreads();
    if (t < 64) {
        float s = zpart[0][t] + zpart[1][t] + zpart[2][t] + zpart[3][t];
        atomicAdd(&zsum[b * K + t], s);
    }
}

// ---------------- EM stage: mu_acc[b,c,k] += sum_p y[b,c,p]*z[b,p,k] --------
__global__ __launch_bounds__(256) void stage_mu(
    const float* __restrict__ y, const float* __restrict__ z,
    float* __restrict__ mu_acc)
{
    int b = blockIdx.z;
    int c0 = blockIdx.y * 64;
    int pstart = blockIdx.x * 640;
    int t = threadIdx.x;
    int k = t & 63, cg = t >> 6;
    __shared__ float yst[16][68];
    __shared__ float zs[16][64];
    float acc[16] = {};
    const float* yb = y + (long)b * CH * NP;
    const float* zb = z + (long)b * NP * K;
    for (int p0 = pstart; p0 < pstart + 640; p0 += 16) {
        __syncthreads();
        {
            int cl = t >> 2, pq = t & 3;
            float4 v = *(const float4*)&yb[(long)(c0 + cl) * NP + p0 + pq * 4];
            yst[pq * 4 + 0][cl] = v.x; yst[pq * 4 + 1][cl] = v.y;
            yst[pq * 4 + 2][cl] = v.z; yst[pq * 4 + 3][cl] = v.w;
        }
        #pragma unroll
        for (int l = t; l < 1024; l += 256) {
            int pp = l >> 6, kk = l & 63;
            zs[pp][kk] = zb[(long)(p0 + pp) * K + kk];
        }
        __syncthreads();
        #pragma unroll
        for (int pp = 0; pp < 16; ++pp) {
            float zv = zs[pp][k];
            const float4* yv = (const float4*)&yst[pp][cg * 16];
            #pragma unroll
            for (int q = 0; q < 4; ++q) {
                float4 v = yv[q];
                acc[q * 4 + 0] += v.x * zv; acc[q * 4 + 1] += v.y * zv;
                acc[q * 4 + 2] += v.z * zv; acc[q * 4 + 3] += v.w * zv;
            }
        }
    }
    float* ma = mu_acc + (long)b * CH * K + (long)c0 * K;
    #pragma unroll
    for (int i = 0; i < 16; ++i)
        atomicAdd(&ma[(cg * 16 + i) * K + k], acc[i]);
}

// ---------------- mu normalize ----------------------------------------------
__global__ __launch_bounds__(256) void mu_norm(const float* __restrict__ acc,
                                               const float* __restrict__ zsum,
                                               float* __restrict__ mu)
{
    int w = blockIdx.x * 4 + (threadIdx.x >> 6);
    int lane = threadIdx.x & 63;
    int b = w >> 6, k = w & 63;
    const float* ab = acc + (long)b * CH * K;
    float s = 0.f;
    for (int c = lane; c < CH; c += 64) { float v = ab[c * K + k]; s += v * v; }
    for (int off = 32; off; off >>= 1) s += __shfl_xor(s, off, 64);
    float d = 1e-6f + zsum[b * K + k];
    float scale = 1.f / (1e-6f * d + sqrtf(s));
    float* mb = mu + (long)b * CH * K;
    for (int c = lane; c < CH; c += 64) mb[c * K + k] = ab[c * K + k] * scale;
}

// ---------------- rec[b,c,p] = relu(sum_k mu[b,c,k] * z[b,p,k]) -------------
__global__ __launch_bounds__(256) void rec_kernel(
    const float* __restrict__ mu, const float* __restrict__ z,
    float* __restrict__ rec)
{
    int b = blockIdx.y;
    int p0 = blockIdx.x * 64;
    int t = threadIdx.x;
    int p = t & 63, cg = t >> 6;
    __shared__ float zs[64][65];
    __shared__ float mst[64][68];
    const float* zb = z + (long)b * NP * K;
    const float* mb = mu + (long)b * CH * K;
    #pragma unroll
    for (int l = t; l < 1024; l += 256) {
        int pr = l >> 4, kq = l & 15;
        float4 v = *(const float4*)&zb[(long)(p0 + pr) * K + kq * 4];
        zs[pr][kq * 4 + 0] = v.x; zs[pr][kq * 4 + 1] = v.y;
        zs[pr][kq * 4 + 2] = v.z; zs[pr][kq * 4 + 3] = v.w;
    }
    float* rb = rec + (long)b * CH * NP;
    for (int c0 = 0; c0 < CH; c0 += 64) {
        __syncthreads();
        #pragma unroll
        for (int l = t; l < 1024; l += 256) {
            int cl = l >> 4, kq = l & 15;
            float4 v = *(const float4*)&mb[(long)(c0 + cl) * K + kq * 4];
            mst[kq * 4 + 0][cl] = v.x; mst[kq * 4 + 1][cl] = v.y;
            mst[kq * 4 + 2][cl] = v.z; mst[kq * 4 + 3][cl] = v.w;
        }
        __syncthreads();
        float acc[16] = {};
        #pragma unroll
        for (int kk = 0; kk < 64; ++kk) {
            float zv = zs[p][kk];
            const float4* mv = (const float4*)&mst[kk][cg * 16];
            #pragma unroll
            for (int q = 0; q < 4; ++q) {
                float4 v = mv[q];
                acc[q * 4 + 0] += v.x * zv; acc[q * 4 + 1] += v.y * zv;
                acc[q * 4 + 2] += v.z * zv; acc[q * 4 + 3] += v.w * zv;
            }
        }
        #pragma unroll
        for (int i = 0; i < 16; ++i)
            rb[(long)(c0 + cg * 16 + i) * NP + p0 + p] = fmaxf(acc[i], 0.f);
    }
}

// ---------------- BN batch stats --------------------------------------------
__global__ __launch_bounds__(256) void bn_stats(const float* __restrict__ y2,
                                                float* __restrict__ stats,
                                                float* __restrict__ statsq)
{
    int d = blockIdx.x;
    int t = threadIdx.x;
    float s = 0.f, sq = 0.f;
    for (int idx = t; idx < BI * HW; idx += 256) {
        int bi = idx >> 10, hw = idx & 1023;
        float v = y2[(long)bi * CH * HW + (long)d * HW + hw];
        s += v; sq += v * v;
    }
    for (int off = 32; off; off >>= 1) {
        s += __shfl_xor(s, off, 64);
        sq += __shfl_xor(sq, off, 64);
    }
    __shared__ float ps[8];
    int wv = t >> 6, ln = t & 63;
    if (ln == 0) { ps[wv] = s; ps[4 + wv] = sq; }
    __syncthreads();
    if (t == 0) {
        stats[d]  = ps[0] + ps[1] + ps[2] + ps[3];
        statsq[d] = ps[4] + ps[5] + ps[6] + ps[7];
    }
}

// ---------------- finale: BN + residual + relu, plus mu_b copy --------------
__global__ __launch_bounds__(256) void final_kernel(
    const float* __restrict__ y2, const float* __restrict__ x,
    const float* __restrict__ stats, const float* __restrict__ statsq,
    const float* __restrict__ gamma, const float* __restrict__ beta,
    const float* __restrict__ mu_cur, float* __restrict__ out)
{
    long i = (long)blockIdx.x * 256 + threadIdx.x;
    const long NMAIN = (long)BI * CH * HW;
    if (i < NMAIN) {
        int d = (int)((i >> 10) & (CH - 1));
        float s = stats[d], sq = statsq[d];
        const float inv = 1.f / (float)(BI * HW);
        float mean = s * inv;
        float var = sq * inv - mean * mean;
        float rs = rsqrtf(var + 1e-5f);
        float v = (y2[i] - mean) * rs * gamma[d] + beta[d] + x[i];
        out[i] = fmaxf(v, 0.f);
    } else if (i < NMAIN + (long)BB * CH * K) {
        out[i] = mu_cur[i - NMAIN];
    }
}

extern "C" void kernel_launch(void* const* d_in, const int* in_sizes, int n_in,
                              void* d_out, int out_size, void* d_ws, size_t ws_size,
                              hipStream_t stream) {
    const float* x   = (const float*)d_in[0];
    const float* mu0 = (const float*)d_in[1];
    const float* w1  = (const float*)d_in[2];
    const float* b1  = (const float*)d_in[3];
    const float* w2  = (const float*)d_in[4];
    const float* gm  = (const float*)d_in[5];
    const float* bt  = (const float*)d_in[6];
    float* out = (float*)d_out;

    float* ws = (float*)d_ws;
    float* y      = ws;                         // 20971520 fp32 (also holds rec)
    float* zbuf   = ws + 20971520;              // 2621440
    float* mu_cur = ws + 23592960;              // 262144
    float* mu_acc = ws + 23855104;              // 262144
    float* zsum   = ws + 24117248;              // 512
    float* stats  = ws + 24117760;              // 512
    float* statsq = ws + 24118272;              // 512
    _Float16* Wh1  = (_Float16*)(ws + 24118784);  // 262144 fp16 = 131072 f-slots
    _Float16* Wh2  = (_Float16*)(ws + 24249856);  // 262144 fp16
    _Float16* Tbuf = (_Float16*)(ws + 24380928);  // 20971520 fp16 (shared xT/recT)
    const size_t needFloats = 34866688;           // end of Tbuf
    float* y2 = out;

    bool mfma_ok = ws_size >= needFloats * sizeof(float);

    if (mfma_ok) {
        wconv<<<1024, 256, 0, stream>>>(w1, Wh1);
        wconv<<<1024, 256, 0, stream>>>(w2, Wh2);
        // xT: per image [1024][512] fp16
        transpose_f16<<<dim3(16, 8, 40), 256, 0, stream>>>(x, Tbuf, HW);
        conv_mfma<<<dim3(16, 8, 40), 256, 0, stream>>>(Wh1, Tbuf, b1, y, 0);
    } else {
        conv_gemm<<<dim3(16, 8, 40), 256, 0, stream>>>(x, w1, b1, y, HW, NP, 0);
    }

    bcast_mu<<<1024, 256, 0, stream>>>(mu0, mu_cur);

    for (int s = 0; s < 5; ++s) {
        hipMemsetAsync(zsum, 0, 512 * sizeof(float), stream);
        hipMemsetAsync(mu_acc, 0, 262144 * sizeof(float), stream);
        stage_z<<<dim3(80, 8), 256, 0, stream>>>(y, mu_cur, zbuf, zsum);
        stage_mu<<<dim3(8, 8, 8), 256, 0, stream>>>(y, zbuf, mu_acc);
        mu_norm<<<128, 256, 0, stream>>>(mu_acc, zsum, mu_cur);
    }

    rec_kernel<<<dim3(80, 8), 256, 0, stream>>>(mu_cur, zbuf, y);

    if (mfma_ok) {
        // recT: per batch [5120][512] fp16
        transpose_f16<<<dim3(80, 8, 8), 256, 0, stream>>>(y, Tbuf, NP);
        conv_mfma<<<dim3(16, 8, 40), 256, 0, stream>>>(Wh2, Tbuf, nullptr, y2, 1);
    } else {
        conv_gemm<<<dim3(16, 8, 40), 256, 0, stream>>>(y, w2, nullptr, y2, NP, HW, 1);
    }

    bn_stats<<<512, 256, 0, stream>>>(y2, stats, statsq);
    long total = (long)BI * CH * HW + (long)BB * CH * K;
    final_kernel<<<(int)((total + 255) / 256), 256, 0, stream>>>(
        y2, x, stats, statsq, gm, bt, mu_cur, out);
}

// Round 5
// 603.131 us; speedup vs baseline: 2.9180x; 2.4702x over previous
//
#include <hip/hip_runtime.h>
#include <math.h>

#define CH 512
#define K 64
#define BB 8
#define NIMG 5
#define HW 1024
#define NP 5120   // NIMG*HW
#define BI 40     // BB*NIMG

typedef __attribute__((ext_vector_type(8))) _Float16 f16x8;
typedef __attribute__((ext_vector_type(4))) _Float16 f16x4;
typedef __attribute__((ext_vector_type(4))) float f32x4;
typedef __attribute__((ext_vector_type(8))) short s16x8;

// ---------------- W fp32 -> fp16 (row-major copy) ---------------------------
__global__ __launch_bounds__(256) void wconv(const float* __restrict__ w,
                                             _Float16* __restrict__ o)
{
    int i = blockIdx.x * 256 + threadIdx.x;   // 262144
    o[i] = (_Float16)w[i];
}

// ---------------- transpose fp32 [z][512][P] -> fp16 [z][P][512] ------------
__global__ __launch_bounds__(256) void transpose_f16(
    const float* __restrict__ in, _Float16* __restrict__ out, int P)
{
    __shared__ float tile[64][65];
    int t = threadIdx.x;
    int p0 = blockIdx.x * 64, c0 = blockIdx.y * 64;
    long ibase = (long)blockIdx.z * CH * P;
    long obase = (long)blockIdx.z * P * CH;
    int pl = t & 63, chh = t >> 6;
    #pragma unroll
    for (int i = 0; i < 16; ++i)
        tile[chh + i * 4][pl] = in[ibase + (long)(c0 + chh + i * 4) * P + p0 + pl];
    __syncthreads();
    int cc = t & 31, pr = t >> 5;
    #pragma unroll
    for (int i = 0; i < 8; ++i) {
        int p = pr + i * 8;
        _Float16 lo = (_Float16)tile[cc * 2][p];
        _Float16 hi = (_Float16)tile[cc * 2 + 1][p];
        unsigned lob = (unsigned)*(unsigned short*)&lo;
        unsigned hib = (unsigned)*(unsigned short*)&hi;
        *(unsigned*)&out[obase + (long)(p0 + p) * CH + c0 + cc * 2] = lob | (hib << 16);
    }
}

// ---------------- broadcast mu -> mu_cur fp32 + muT fp16 --------------------
__global__ __launch_bounds__(256) void bcast_mu2(const float* __restrict__ mu_in,
                                                 float* __restrict__ mu_cur,
                                                 _Float16* __restrict__ muT)
{
    int i = blockIdx.x * 256 + threadIdx.x;   // [b][c][k], 262144
    float v = mu_in[i & 32767];
    mu_cur[i] = v;
    int b = i >> 15, ck = i & 32767, c = ck >> 6, k = ck & 63;
    muT[((long)b << 15) + k * CH + c] = (_Float16)v;
}

// ---------------- conv via MFMA: out[d,p] = sum_c W[d,c]*inT[p,c] -----------
// per wave: 32 d x 128 p (16 accs). mode 0 = conv1 (writes y16+yT16, +bias),
// mode 1 = conv2 (writes y2 fp32).
__global__ __launch_bounds__(256) void conv_mfma2(
    const _Float16* __restrict__ Wh, const _Float16* __restrict__ inT,
    const float* __restrict__ bias, float* __restrict__ y2,
    _Float16* __restrict__ y16, _Float16* __restrict__ yT16, int mode)
{
    int t = threadIdx.x;
    int lane = t & 63, w = t >> 6;
    int l15 = lane & 15, l4 = lane >> 4;
    int bi = blockIdx.z;
    int d0 = blockIdx.y * 128 + w * 32;
    int pimg = blockIdx.x * 128;
    long inRow0 = (mode == 0) ? ((long)bi * HW + pimg)
                              : ((long)(bi / NIMG) * NP + (long)(bi % NIMG) * HW + pimg);
    const _Float16* Aa = Wh + (long)(d0 + l15) * CH + l4 * 8;
    const _Float16* Bb = inT + (inRow0 + l15) * (long)CH + l4 * 8;
    f32x4 acc[2][8];
    #pragma unroll
    for (int dj = 0; dj < 2; ++dj)
        #pragma unroll
        for (int pj = 0; pj < 8; ++pj) acc[dj][pj] = (f32x4){0.f, 0.f, 0.f, 0.f};
    #pragma unroll 2
    for (int c0 = 0; c0 < CH; c0 += 32) {
        f16x8 a0 = *(const f16x8*)(Aa + c0);
        f16x8 a1 = *(const f16x8*)(Aa + 16 * CH + c0);
        #pragma unroll
        for (int pj = 0; pj < 8; ++pj) {
            f16x8 bv = *(const f16x8*)(Bb + pj * 16 * CH + c0);
            acc[0][pj] = __builtin_amdgcn_mfma_f32_16x16x32_f16(a0, bv, acc[0][pj], 0, 0, 0);
            acc[1][pj] = __builtin_amdgcn_mfma_f32_16x16x32_f16(a1, bv, acc[1][pj], 0, 0, 0);
        }
    }
    // C/D: col = l15 (B-row = p), row = l4*4+i (A-row = d)
    if (mode == 0) {
        int b = bi / NIMG;
        int pbase = (bi % NIMG) * HW + pimg;
        #pragma unroll
        for (int dj = 0; dj < 2; ++dj) {
            int dd = d0 + dj * 16 + l4 * 4;
            float b0 = bias[dd], b1 = bias[dd + 1], b2 = bias[dd + 2], b3 = bias[dd + 3];
            #pragma unroll
            for (int pj = 0; pj < 8; ++pj) {
                int pb = pbase + pj * 16 + l15;
                f16x4 pk = { (_Float16)(acc[dj][pj][0] + b0), (_Float16)(acc[dj][pj][1] + b1),
                             (_Float16)(acc[dj][pj][2] + b2), (_Float16)(acc[dj][pj][3] + b3) };
                *(f16x4*)&yT16[((long)b * NP + pb) * CH + dd] = pk;
                long ybase = ((long)b * CH + dd) * NP + pb;
                y16[ybase] = pk[0];
                y16[ybase + NP] = pk[1];
                y16[ybase + 2 * NP] = pk[2];
                y16[ybase + 3 * NP] = pk[3];
            }
        }
    } else {
        long obase = (long)bi * CH * HW + pimg;
        #pragma unroll
        for (int dj = 0; dj < 2; ++dj) {
            int dd = d0 + dj * 16 + l4 * 4;
            #pragma unroll
            for (int pj = 0; pj < 8; ++pj) {
                long o = obase + (long)dd * HW + pj * 16 + l15;
                y2[o] = acc[dj][pj][0];
                y2[o + HW] = acc[dj][pj][1];
                y2[o + 2 * HW] = acc[dj][pj][2];
                y2[o + 3 * HW] = acc[dj][pj][3];
            }
        }
    }
}

// ---------------- EM: S=yT*muT (MFMA) + softmax + zT/z16/zsum ---------------
__global__ __launch_bounds__(256) void stage_z_mfma(
    const _Float16* __restrict__ yT, const _Float16* __restrict__ muT,
    _Float16* __restrict__ zT, _Float16* __restrict__ z16,
    float* __restrict__ zsum, int writeZ)
{
    __shared__ _Float16 ms[32768];   // frag-order muT: [chunk16][j4][lane64][8] = 64KB
    int t = threadIdx.x;
    int w = t >> 6, lane = t & 63, l15 = lane & 15, l4 = lane >> 4;
    int p0 = blockIdx.x * 64;
    int b = blockIdx.y;
    const _Float16* mb = muT + ((long)b << 15);
    #pragma unroll
    for (int it = 0; it < 16; ++it) {
        int sl = t + it * 256;
        int cc = sl >> 8, j = (sl >> 6) & 3, ln = sl & 63;
        int rl15 = ln & 15, rl4 = ln >> 4;
        *(s16x8*)&ms[sl * 8] = *(const s16x8*)&mb[(rl15 + 16 * j) * CH + cc * 32 + rl4 * 8];
    }
    const _Float16* arow = yT + ((long)b * NP + p0 + w * 16 + l15) * CH + l4 * 8;
    f32x4 acc[4];
    #pragma unroll
    for (int j = 0; j < 4; ++j) acc[j] = (f32x4){0.f, 0.f, 0.f, 0.f};
    __syncthreads();
    #pragma unroll
    for (int cc = 0; cc < 16; ++cc) {
        f16x8 a = *(const f16x8*)(arow + cc * 32);
        #pragma unroll
        for (int j = 0; j < 4; ++j) {
            f16x8 bj = *(const f16x8*)&ms[((cc * 4 + j) * 64 + lane) * 8];
            acc[j] = __builtin_amdgcn_mfma_f32_16x16x32_f16(a, bj, acc[j], 0, 0, 0);
        }
    }
    // lane holds S[p = p0+w*16+l4*4+i][k = l15+16j]; softmax over k per p-row.
    float zv[4][4];
    #pragma unroll
    for (int i = 0; i < 4; ++i) {
        float m = fmaxf(fmaxf(acc[0][i], acc[1][i]), fmaxf(acc[2][i], acc[3][i]));
        #pragma unroll
        for (int off = 1; off < 16; off <<= 1) m = fmaxf(m, __shfl_xor(m, off, 64));
        float e0 = __expf(acc[0][i] - m);
        float e1 = __expf(acc[1][i] - m);
        float e2 = __expf(acc[2][i] - m);
        float e3 = __expf(acc[3][i] - m);
        float s = e0 + e1 + e2 + e3;
        #pragma unroll
        for (int off = 1; off < 16; off <<= 1) s += __shfl_xor(s, off, 64);
        float inv = 1.f / s;
        zv[0][i] = e0 * inv; zv[1][i] = e1 * inv; zv[2][i] = e2 * inv; zv[3][i] = e3 * inv;
    }
    int prow = p0 + w * 16 + l4 * 4;
    long ztbase = (long)b * K * NP;
    #pragma unroll
    for (int j = 0; j < 4; ++j) {
        f16x4 pk = { (_Float16)zv[j][0], (_Float16)zv[j][1],
                     (_Float16)zv[j][2], (_Float16)zv[j][3] };
        *(f16x4*)&zT[ztbase + (long)(l15 + 16 * j) * NP + prow] = pk;
    }
    if (writeZ) {
        long zbase = (long)b * NP * K;
        #pragma unroll
        for (int j = 0; j < 4; ++j)
            #pragma unroll
            for (int i = 0; i < 4; ++i)
                z16[zbase + (long)(prow + i) * K + l15 + 16 * j] = (_Float16)zv[j][i];
    }
    float part[4];
    #pragma unroll
    for (int j = 0; j < 4; ++j) {
        part[j] = zv[j][0] + zv[j][1] + zv[j][2] + zv[j][3];
        part[j] += __shfl_xor(part[j], 16, 64);
        part[j] += __shfl_xor(part[j], 32, 64);
    }
    __syncthreads();                 // ms no longer needed -> reuse as zred
    float* zred = (float*)ms;
    if (l4 == 0) {
        #pragma unroll
        for (int j = 0; j < 4; ++j) zred[w * 64 + l15 + 16 * j] = part[j];
    }
    __syncthreads();
    if (t < 64)
        atomicAdd(&zsum[b * 64 + t], zred[t] + zred[64 + t] + zred[128 + t] + zred[192 + t]);
}

// ---------------- EM: macc[pc][b][k][c] = sum_p y16[c][p]*zT[k][p] ----------
__global__ __launch_bounds__(256) void stage_mu_mfma(
    const _Float16* __restrict__ y16, const _Float16* __restrict__ zT,
    float* __restrict__ macc)
{
    __shared__ _Float16 zs[2048];    // frag-order: [j4][lane64][8] = 4KB
    int t = threadIdx.x;
    int w = t >> 6, lane = t & 63, l15 = lane & 15, l4 = lane >> 4;
    int pc = blockIdx.x, ct = blockIdx.y, b = blockIdx.z;
    int pbase = pc * 640;
    const _Float16* zsrc = zT + (long)b * K * NP + (long)(l15 + 16 * w) * NP + l4 * 8;
    const _Float16* arow = y16 + ((long)b * CH + ct * 64 + w * 16 + l15) * NP + l4 * 8;
    f32x4 acc[4];
    #pragma unroll
    for (int j = 0; j < 4; ++j) acc[j] = (f32x4){0.f, 0.f, 0.f, 0.f};
    for (int p0 = pbase; p0 < pbase + 640; p0 += 32) {
        __syncthreads();
        *(s16x8*)&zs[t * 8] = *(const s16x8*)(zsrc + p0);
        __syncthreads();
        f16x8 a = *(const f16x8*)(arow + p0);
        #pragma unroll
        for (int j = 0; j < 4; ++j) {
            f16x8 bj = *(const f16x8*)&zs[(j * 64 + lane) * 8];
            acc[j] = __builtin_amdgcn_mfma_f32_16x16x32_f16(a, bj, acc[j], 0, 0, 0);
        }
    }
    // output: row (A) = c = ct*64+w*16+l4*4+i, col (B) = k = l15+16j
    float* mp = macc + ((long)pc * BB + b) * K * CH;
    #pragma unroll
    for (int j = 0; j < 4; ++j)
        *(f32x4*)&mp[(long)(l15 + 16 * j) * CH + ct * 64 + w * 16 + l4 * 4] = acc[j];
}

// ---------------- mu normalize: sum partials, l2norm, emit 3 formats --------
__global__ __launch_bounds__(256) void mu_norm2(
    const float* __restrict__ macc, const float* __restrict__ zsum,
    float* __restrict__ mu_cur, _Float16* __restrict__ mu16,
    _Float16* __restrict__ muT)
{
    int gw = blockIdx.x * 4 + (threadIdx.x >> 6);   // 512 = 8b x 64k
    int lane = threadIdx.x & 63;
    int b = gw >> 6, k = gw & 63;
    float v[8];
    float s = 0.f;
    #pragma unroll
    for (int ci = 0; ci < 8; ++ci) {
        int c = ci * 64 + lane;
        float a = 0.f;
        #pragma unroll
        for (int pcc = 0; pcc < 8; ++pcc)
            a += macc[(((long)pcc * BB + b) * K + k) * CH + c];
        v[ci] = a; s += a * a;
    }
    #pragma unroll
    for (int off = 1; off < 64; off <<= 1) s += __shfl_xor(s, off, 64);
    float d = 1e-6f + zsum[b * 64 + k];
    float scale = 1.f / (1e-6f * d + sqrtf(s));
    long mb = (long)b << 15;
    #pragma unroll
    for (int ci = 0; ci < 8; ++ci) {
        int c = ci * 64 + lane;
        float m = v[ci] * scale;
        mu_cur[mb + (long)c * K + k] = m;
        mu16[mb + (long)c * K + k] = (_Float16)m;
        muT[mb + (long)k * CH + c] = (_Float16)m;
    }
}

// ---------------- rec: recT[p][c] = relu(sum_k z16[p][k]*mu16[c][k]) --------
__global__ __launch_bounds__(256) void rec_mfma(
    const _Float16* __restrict__ z16, const _Float16* __restrict__ mu16,
    _Float16* __restrict__ recT)
{
    __shared__ _Float16 rt[64 * 80];
    int t = threadIdx.x;
    int w = t >> 6, lane = t & 63, l15 = lane & 15, l4 = lane >> 4;
    int p0 = blockIdx.x * 64, ct = blockIdx.y, b = blockIdx.z;
    const _Float16* zb = z16 + (long)b * NP * K;
    const _Float16* mb = mu16 + ((long)b << 15) + (long)(ct * 64 + w * 16 + l15) * K + l4 * 8;
    f32x4 acc[4];
    #pragma unroll
    for (int pj = 0; pj < 4; ++pj) acc[pj] = (f32x4){0.f, 0.f, 0.f, 0.f};
    #pragma unroll
    for (int kc = 0; kc < 64; kc += 32) {
        f16x8 bfr = *(const f16x8*)(mb + kc);
        #pragma unroll
        for (int pj = 0; pj < 4; ++pj) {
            f16x8 a = *(const f16x8*)(zb + (long)(p0 + pj * 16 + l15) * K + kc + l4 * 8);
            acc[pj] = __builtin_amdgcn_mfma_f32_16x16x32_f16(a, bfr, acc[pj], 0, 0, 0);
        }
    }
    // row (A) = p_local = pj*16+l4*4+i, col (B) = c_local = w*16+l15
    #pragma unroll
    for (int pj = 0; pj < 4; ++pj)
        #pragma unroll
        for (int i = 0; i < 4; ++i)
            rt[(pj * 16 + l4 * 4 + i) * 80 + w * 16 + l15] = (_Float16)fmaxf(acc[pj][i], 0.f);
    __syncthreads();
    #pragma unroll
    for (int it = 0; it < 2; ++it) {
        int l = t + it * 256;
        int row = l >> 3, s8 = l & 7;
        *(s16x8*)&recT[((long)b * NP + p0 + row) * CH + ct * 64 + s8 * 8] =
            *(const s16x8*)&rt[row * 80 + s8 * 8];
    }
}

// ---------------- BN batch stats --------------------------------------------
__global__ __launch_bounds__(256) void bn_stats(const float* __restrict__ y2,
                                                float* __restrict__ stats,
                                                float* __restrict__ statsq)
{
    int d = blockIdx.x;
    int t = threadIdx.x;
    float s = 0.f, sq = 0.f;
    for (int idx = t; idx < BI * HW; idx += 256) {
        int bi = idx >> 10, hw = idx & 1023;
        float v = y2[(long)bi * CH * HW + (long)d * HW + hw];
        s += v; sq += v * v;
    }
    for (int off = 32; off; off >>= 1) {
        s += __shfl_xor(s, off, 64);
        sq += __shfl_xor(sq, off, 64);
    }
    __shared__ float ps[8];
    int wv = t >> 6, ln = t & 63;
    if (ln == 0) { ps[wv] = s; ps[4 + wv] = sq; }
    __syncthreads();
    if (t == 0) {
        stats[d]  = ps[0] + ps[1] + ps[2] + ps[3];
        statsq[d] = ps[4] + ps[5] + ps[6] + ps[7];
    }
}

// ---------------- finale: BN + residual + relu, plus mu_b copy --------------
__global__ __launch_bounds__(256) void final_kernel(
    const float* __restrict__ y2, const float* __restrict__ x,
    const float* __restrict__ stats, const float* __restrict__ statsq,
    const float* __restrict__ gamma, const float* __restrict__ beta,
    const float* __restrict__ mu_cur, float* __restrict__ out)
{
    long i = (long)blockIdx.x * 256 + threadIdx.x;
    const long NMAIN = (long)BI * CH * HW;
    if (i < NMAIN) {
        int d = (int)((i >> 10) & (CH - 1));
        float s = stats[d], sq = statsq[d];
        const float inv = 1.f / (float)(BI * HW);
        float mean = s * inv;
        float var = sq * inv - mean * mean;
        float rs = rsqrtf(var + 1e-5f);
        float v = (y2[i] - mean) * rs * gamma[d] + beta[d] + x[i];
        out[i] = fmaxf(v, 0.f);
    } else if (i < NMAIN + (long)BB * CH * K) {
        out[i] = mu_cur[i - NMAIN];
    }
}

extern "C" void kernel_launch(void* const* d_in, const int* in_sizes, int n_in,
                              void* d_out, int out_size, void* d_ws, size_t ws_size,
                              hipStream_t stream) {
    const float* x   = (const float*)d_in[0];
    const float* mu0 = (const float*)d_in[1];
    const float* w1  = (const float*)d_in[2];
    const float* b1  = (const float*)d_in[3];
    const float* w2  = (const float*)d_in[4];
    const float* gm  = (const float*)d_in[5];
    const float* bt  = (const float*)d_in[6];
    float* out = (float*)d_out;

    float* ws = (float*)d_ws;
    // fp16 regions (sizes in float-slots)
    _Float16* y16h  = (_Float16*)(ws);              // [8][512][5120]  10,485,760 f
    _Float16* yT16h = (_Float16*)(ws + 10485760);   // [8][5120][512]  (reused as recT)
    _Float16* xTh   = (_Float16*)(ws + 20971520);   // [40960][512]    10,485,760 f
    _Float16* zTh   = (_Float16*)(ws + 20971520);   // [8][64][5120]   1,310,720 f (reuses xT)
    _Float16* z16h  = (_Float16*)(ws + 22282240);   // [8][5120][64]   1,310,720 f
    float*    macc  = ws + 23592960;                // [8][8][64][512] 2,097,152 f
    float*    mu_cur = ws + 31457280;               // 262,144 f
    _Float16* Wh1   = (_Float16*)(ws + 31719424);   // 131,072 f
    _Float16* Wh2   = (_Float16*)(ws + 31850496);   // 131,072 f
    _Float16* mu16h = (_Float16*)(ws + 31981568);   // 131,072 f
    _Float16* muTh  = (_Float16*)(ws + 32112640);   // 131,072 f
    float*    zsum  = ws + 32243712;                // 512
    float*    stats = ws + 32244224;                // 512
    float*    statsq = ws + 32244736;               // 512
    float* y2 = out;

    wconv<<<1024, 256, 0, stream>>>(w1, Wh1);
    wconv<<<1024, 256, 0, stream>>>(w2, Wh2);
    transpose_f16<<<dim3(16, 8, 40), 256, 0, stream>>>(x, xTh, HW);
    conv_mfma2<<<dim3(8, 4, 40), 256, 0, stream>>>(Wh1, xTh, b1, nullptr, y16h, yT16h, 0);
    bcast_mu2<<<1024, 256, 0, stream>>>(mu0, mu_cur, muTh);

    for (int s = 0; s < 5; ++s) {
        hipMemsetAsync(zsum, 0, 512 * sizeof(float), stream);
        stage_z_mfma<<<dim3(80, 8), 256, 0, stream>>>(yT16h, muTh, zTh, z16h, zsum, s == 4);
        stage_mu_mfma<<<dim3(8, 8, 8), 256, 0, stream>>>(y16h, zTh, macc);
        mu_norm2<<<128, 256, 0, stream>>>(macc, zsum, mu_cur, mu16h, muTh);
    }

    // rec overwrites yT16 region (dead after last stage_z)
    rec_mfma<<<dim3(80, 8, 8), 256, 0, stream>>>(z16h, mu16h, yT16h);
    conv_mfma2<<<dim3(8, 4, 40), 256, 0, stream>>>(Wh2, yT16h, nullptr, y2, nullptr, nullptr, 1);
    bn_stats<<<512, 256, 0, stream>>>(y2, stats, statsq);
    long total = (long)BI * CH * HW + (long)BB * CH * K;
    final_kernel<<<(int)((total + 255) / 256), 256, 0, stream>>>(
        y2, x, stats, statsq, gm, bt, mu_cur, out);
}

// Round 6
// 492.943 us; speedup vs baseline: 3.5702x; 1.2235x over previous
//
#include <hip/hip_runtime.h>
#include <math.h>

#define CH 512
#define K 64
#define BB 8
#define NIMG 5
#define HW 1024
#define NP 5120   // NIMG*HW
#define BI 40     // BB*NIMG

typedef __attribute__((ext_vector_type(8))) _Float16 f16x8;
typedef __attribute__((ext_vector_type(4))) _Float16 f16x4;
typedef __attribute__((ext_vector_type(4))) float f32x4;
typedef __attribute__((ext_vector_type(8))) short s16x8;

#define AS1 __attribute__((address_space(1)))
#define AS3 __attribute__((address_space(3)))

// ---------------- W fp32 -> fp16 (row-major copy) ---------------------------
__global__ __launch_bounds__(256) void wconv(const float* __restrict__ w,
                                             _Float16* __restrict__ o)
{
    int i = blockIdx.x * 256 + threadIdx.x;   // 262144
    o[i] = (_Float16)w[i];
}

// ---------------- transpose fp32 [z][512][P] -> fp16 [z][P][512] ------------
__global__ __launch_bounds__(256) void transpose_f16(
    const float* __restrict__ in, _Float16* __restrict__ out, int P)
{
    __shared__ float tile[64][65];
    int t = threadIdx.x;
    int p0 = blockIdx.x * 64, c0 = blockIdx.y * 64;
    long ibase = (long)blockIdx.z * CH * P;
    long obase = (long)blockIdx.z * P * CH;
    int pl = t & 63, chh = t >> 6;
    #pragma unroll
    for (int i = 0; i < 16; ++i)
        tile[chh + i * 4][pl] = in[ibase + (long)(c0 + chh + i * 4) * P + p0 + pl];
    __syncthreads();
    int cc = t & 31, pr = t >> 5;
    #pragma unroll
    for (int i = 0; i < 8; ++i) {
        int p = pr + i * 8;
        _Float16 lo = (_Float16)tile[cc * 2][p];
        _Float16 hi = (_Float16)tile[cc * 2 + 1][p];
        unsigned lob = (unsigned)*(unsigned short*)&lo;
        unsigned hib = (unsigned)*(unsigned short*)&hi;
        *(unsigned*)&out[obase + (long)(p0 + p) * CH + c0 + cc * 2] = lob | (hib << 16);
    }
}

// ---------------- broadcast mu -> mu_cur fp32 + muT fp16 --------------------
__global__ __launch_bounds__(256) void bcast_mu2(const float* __restrict__ mu_in,
                                                 float* __restrict__ mu_cur,
                                                 _Float16* __restrict__ muT)
{
    int i = blockIdx.x * 256 + threadIdx.x;   // [b][c][k], 262144
    float v = mu_in[i & 32767];
    mu_cur[i] = v;
    int b = i >> 15, ck = i & 32767, c = ck >> 6, k = ck & 63;
    muT[((long)b << 15) + k * CH + c] = (_Float16)v;
}

// ---------------- conv via m97-style tiled MFMA -----------------------------
// out[d,p] = sum_c W[d,c] * inT[p,c].  128d x 128p tile, BK=64, 4 waves,
// global_load_lds(16B) staging with XOR-swizzled source; swizzled ds_read.
// mode 0 = conv1 (writes y16 + yT16, +bias); mode 1 = conv2 (writes y2 fp32).
__global__ __launch_bounds__(256) void conv_tile(
    const _Float16* __restrict__ Wh, const _Float16* __restrict__ inT,
    const float* __restrict__ bias, float* __restrict__ y2,
    _Float16* __restrict__ y16, _Float16* __restrict__ yT16, int mode)
{
    __shared__ _Float16 Wt[128 * 64];   // 16 KB, swizzled storage
    __shared__ _Float16 Xt[128 * 64];   // 16 KB
    int t = threadIdx.x;
    int lane = t & 63, w = t >> 6;
    int l15 = lane & 15, l4 = lane >> 4;
    int wd = w & 1, wp = w >> 1;        // wave quadrant: 64d x 64p
    int bi = blockIdx.z;
    int d0 = blockIdx.y * 128;
    int pl0 = blockIdx.x * 128;         // p within image
    long prow0 = (long)bi * HW + pl0;   // row in inT (valid for both modes)
    int ci_row = lane >> 3;             // sub-row within an 8-row gll call
    int colb_phys = (lane & 7) * 16;    // physical byte col this lane fills

    f32x4 acc[4][4];
    #pragma unroll
    for (int ai = 0; ai < 4; ++ai)
        #pragma unroll
        for (int bj = 0; bj < 4; ++bj) acc[ai][bj] = (f32x4){0.f, 0.f, 0.f, 0.f};

    for (int c0 = 0; c0 < CH; c0 += 64) {
        __syncthreads();   // previous tile fully consumed
        #pragma unroll
        for (int i = 0; i < 4; ++i) {
            int row = w * 32 + i * 8 + ci_row;
            int cb = colb_phys ^ ((row & 7) << 4);   // logical byte col (involution)
            const _Float16* srcW = Wh + (long)(d0 + row) * CH + c0 + (cb >> 1);
            const _Float16* srcX = inT + (prow0 + row) * (long)CH + c0 + (cb >> 1);
            __builtin_amdgcn_global_load_lds((const AS1 void*)srcW,
                (AS3 void*)&Wt[(w * 32 + i * 8) * 64], 16, 0, 0);
            __builtin_amdgcn_global_load_lds((const AS1 void*)srcX,
                (AS3 void*)&Xt[(w * 32 + i * 8) * 64], 16, 0, 0);
        }
        __syncthreads();   // vmcnt(0) drained by barrier -> tile visible
        #pragma unroll
        for (int kk = 0; kk < 2; ++kk) {
            f16x8 af[4], bf[4];
            #pragma unroll
            for (int ai = 0; ai < 4; ++ai) {
                int row = wd * 64 + ai * 16 + l15;
                int cb = (kk * 64 + l4 * 16) ^ ((row & 7) << 4);
                af[ai] = *(const f16x8*)((const char*)Wt + row * 128 + cb);
            }
            #pragma unroll
            for (int bj = 0; bj < 4; ++bj) {
                int row = wp * 64 + bj * 16 + l15;
                int cb = (kk * 64 + l4 * 16) ^ ((row & 7) << 4);
                bf[bj] = *(const f16x8*)((const char*)Xt + row * 128 + cb);
            }
            #pragma unroll
            for (int ai = 0; ai < 4; ++ai)
                #pragma unroll
                for (int bj = 0; bj < 4; ++bj)
                    acc[ai][bj] = __builtin_amdgcn_mfma_f32_16x16x32_f16(
                        af[ai], bf[bj], acc[ai][bj], 0, 0, 0);
        }
    }

    // C/D: col = l15 (p within 16-block), row = l4*4 + reg (d)
    int b = bi / NIMG, n = bi % NIMG;
    if (mode == 0) {
        #pragma unroll
        for (int ai = 0; ai < 4; ++ai) {
            int dd = d0 + wd * 64 + ai * 16 + l4 * 4;
            float b0 = bias[dd], b1 = bias[dd + 1], b2 = bias[dd + 2], b3 = bias[dd + 3];
            #pragma unroll
            for (int bj = 0; bj < 4; ++bj) {
                int pb = n * HW + pl0 + wp * 64 + bj * 16 + l15;
                f16x4 pk = { (_Float16)(acc[ai][bj][0] + b0), (_Float16)(acc[ai][bj][1] + b1),
                             (_Float16)(acc[ai][bj][2] + b2), (_Float16)(acc[ai][bj][3] + b3) };
                *(f16x4*)&yT16[((long)b * NP + pb) * CH + dd] = pk;
                long yb = ((long)b * CH + dd) * NP + pb;
                y16[yb] = pk[0];
                y16[yb + NP] = pk[1];
                y16[yb + 2 * NP] = pk[2];
                y16[yb + 3 * NP] = pk[3];
            }
        }
    } else {
        long obase = (long)bi * CH * HW;
        #pragma unroll
        for (int ai = 0; ai < 4; ++ai) {
            int dd = d0 + wd * 64 + ai * 16 + l4 * 4;
            #pragma unroll
            for (int bj = 0; bj < 4; ++bj) {
                int p = pl0 + wp * 64 + bj * 16 + l15;
                long o = obase + (long)dd * HW + p;
                y2[o] = acc[ai][bj][0];
                y2[o + HW] = acc[ai][bj][1];
                y2[o + 2 * HW] = acc[ai][bj][2];
                y2[o + 3 * HW] = acc[ai][bj][3];
            }
        }
    }
}

// ---------------- EM: S=yT*muT (MFMA) + softmax + zT/z16/zsum ---------------
__global__ __launch_bounds__(256) void stage_z_mfma(
    const _Float16* __restrict__ yT, const _Float16* __restrict__ muT,
    _Float16* __restrict__ zT, _Float16* __restrict__ z16,
    float* __restrict__ zsum, int writeZ)
{
    __shared__ _Float16 ms[32768];   // frag-order muT: [chunk16][j4][lane64][8] = 64KB
    int t = threadIdx.x;
    int w = t >> 6, lane = t & 63, l15 = lane & 15, l4 = lane >> 4;
    int p0 = blockIdx.x * 64;
    int b = blockIdx.y;
    const _Float16* mb = muT + ((long)b << 15);
    #pragma unroll
    for (int it = 0; it < 16; ++it) {
        int sl = t + it * 256;
        int cc = sl >> 8, j = (sl >> 6) & 3, ln = sl & 63;
        int rl15 = ln & 15, rl4 = ln >> 4;
        *(s16x8*)&ms[sl * 8] = *(const s16x8*)&mb[(rl15 + 16 * j) * CH + cc * 32 + rl4 * 8];
    }
    const _Float16* arow = yT + ((long)b * NP + p0 + w * 16 + l15) * CH + l4 * 8;
    f32x4 acc[4];
    #pragma unroll
    for (int j = 0; j < 4; ++j) acc[j] = (f32x4){0.f, 0.f, 0.f, 0.f};
    __syncthreads();
    #pragma unroll
    for (int cc = 0; cc < 16; ++cc) {
        f16x8 a = *(const f16x8*)(arow + cc * 32);
        #pragma unroll
        for (int j = 0; j < 4; ++j) {
            f16x8 bj = *(const f16x8*)&ms[((cc * 4 + j) * 64 + lane) * 8];
            acc[j] = __builtin_amdgcn_mfma_f32_16x16x32_f16(a, bj, acc[j], 0, 0, 0);
        }
    }
    // lane holds S[p = p0+w*16+l4*4+i][k = l15+16j]; softmax over k per p-row.
    float zv[4][4];
    #pragma unroll
    for (int i = 0; i < 4; ++i) {
        float m = fmaxf(fmaxf(acc[0][i], acc[1][i]), fmaxf(acc[2][i], acc[3][i]));
        #pragma unroll
        for (int off = 1; off < 16; off <<= 1) m = fmaxf(m, __shfl_xor(m, off, 64));
        float e0 = __expf(acc[0][i] - m);
        float e1 = __expf(acc[1][i] - m);
        float e2 = __expf(acc[2][i] - m);
        float e3 = __expf(acc[3][i] - m);
        float s = e0 + e1 + e2 + e3;
        #pragma unroll
        for (int off = 1; off < 16; off <<= 1) s += __shfl_xor(s, off, 64);
        float inv = 1.f / s;
        zv[0][i] = e0 * inv; zv[1][i] = e1 * inv; zv[2][i] = e2 * inv; zv[3][i] = e3 * inv;
    }
    int prow = p0 + w * 16 + l4 * 4;
    long ztbase = (long)b * K * NP;
    #pragma unroll
    for (int j = 0; j < 4; ++j) {
        f16x4 pk = { (_Float16)zv[j][0], (_Float16)zv[j][1],
                     (_Float16)zv[j][2], (_Float16)zv[j][3] };
        *(f16x4*)&zT[ztbase + (long)(l15 + 16 * j) * NP + prow] = pk;
    }
    if (writeZ) {
        long zbase = (long)b * NP * K;
        #pragma unroll
        for (int j = 0; j < 4; ++j)
            #pragma unroll
            for (int i = 0; i < 4; ++i)
                z16[zbase + (long)(prow + i) * K + l15 + 16 * j] = (_Float16)zv[j][i];
    }
    float part[4];
    #pragma unroll
    for (int j = 0; j < 4; ++j) {
        part[j] = zv[j][0] + zv[j][1] + zv[j][2] + zv[j][3];
        part[j] += __shfl_xor(part[j], 16, 64);
        part[j] += __shfl_xor(part[j], 32, 64);
    }
    __syncthreads();                 // ms no longer needed -> reuse as zred
    float* zred = (float*)ms;
    if (l4 == 0) {
        #pragma unroll
        for (int j = 0; j < 4; ++j) zred[w * 64 + l15 + 16 * j] = part[j];
    }
    __syncthreads();
    if (t < 64)
        atomicAdd(&zsum[b * 64 + t], zred[t] + zred[64 + t] + zred[128 + t] + zred[192 + t]);
}

// ---------------- EM: macc[pc][b][k][c] = sum_p y16[c][p]*zT[k][p] ----------
__global__ __launch_bounds__(256) void stage_mu_mfma(
    const _Float16* __restrict__ y16, const _Float16* __restrict__ zT,
    float* __restrict__ macc)
{
    __shared__ _Float16 zs[2048];    // frag-order: [j4][lane64][8] = 4KB
    int t = threadIdx.x;
    int w = t >> 6, lane = t & 63, l15 = lane & 15, l4 = lane >> 4;
    int pc = blockIdx.x, ct = blockIdx.y, b = blockIdx.z;
    int pbase = pc * 640;
    const _Float16* zsrc = zT + (long)b * K * NP + (long)(l15 + 16 * w) * NP + l4 * 8;
    const _Float16* arow = y16 + ((long)b * CH + ct * 64 + w * 16 + l15) * NP + l4 * 8;
    f32x4 acc[4];
    #pragma unroll
    for (int j = 0; j < 4; ++j) acc[j] = (f32x4){0.f, 0.f, 0.f, 0.f};
    for (int p0 = pbase; p0 < pbase + 640; p0 += 32) {
        __syncthreads();
        *(s16x8*)&zs[t * 8] = *(const s16x8*)(zsrc + p0);
        __syncthreads();
        f16x8 a = *(const f16x8*)(arow + p0);
        #pragma unroll
        for (int j = 0; j < 4; ++j) {
            f16x8 bj = *(const f16x8*)&zs[(j * 64 + lane) * 8];
            acc[j] = __builtin_amdgcn_mfma_f32_16x16x32_f16(a, bj, acc[j], 0, 0, 0);
        }
    }
    // output: row (A) = c = ct*64+w*16+l4*4+i, col (B) = k = l15+16j
    float* mp = macc + ((long)pc * BB + b) * K * CH;
    #pragma unroll
    for (int j = 0; j < 4; ++j)
        *(f32x4*)&mp[(long)(l15 + 16 * j) * CH + ct * 64 + w * 16 + l4 * 4] = acc[j];
}

// ---------------- mu normalize: sum partials, l2norm, emit 3 formats --------
__global__ __launch_bounds__(256) void mu_norm2(
    const float* __restrict__ macc, const float* __restrict__ zsum,
    float* __restrict__ mu_cur, _Float16* __restrict__ mu16,
    _Float16* __restrict__ muT)
{
    int gw = blockIdx.x * 4 + (threadIdx.x >> 6);   // 512 = 8b x 64k
    int lane = threadIdx.x & 63;
    int b = gw >> 6, k = gw & 63;
    float v[8];
    float s = 0.f;
    #pragma unroll
    for (int ci = 0; ci < 8; ++ci) {
        int c = ci * 64 + lane;
        float a = 0.f;
        #pragma unroll
        for (int pcc = 0; pcc < 8; ++pcc)
            a += macc[(((long)pcc * BB + b) * K + k) * CH + c];
        v[ci] = a; s += a * a;
    }
    #pragma unroll
    for (int off = 1; off < 64; off <<= 1) s += __shfl_xor(s, off, 64);
    float d = 1e-6f + zsum[b * 64 + k];
    float scale = 1.f / (1e-6f * d + sqrtf(s));
    long mb = (long)b << 15;
    #pragma unroll
    for (int ci = 0; ci < 8; ++ci) {
        int c = ci * 64 + lane;
        float m = v[ci] * scale;
        mu_cur[mb + (long)c * K + k] = m;
        mu16[mb + (long)c * K + k] = (_Float16)m;
        muT[mb + (long)k * CH + c] = (_Float16)m;
    }
}

// ---------------- rec: recT[p][c] = relu(sum_k z16[p][k]*mu16[c][k]) --------
__global__ __launch_bounds__(256) void rec_mfma(
    const _Float16* __restrict__ z16, const _Float16* __restrict__ mu16,
    _Float16* __restrict__ recT)
{
    __shared__ _Float16 rt[64 * 80];
    int t = threadIdx.x;
    int w = t >> 6, lane = t & 63, l15 = lane & 15, l4 = lane >> 4;
    int p0 = blockIdx.x * 64, ct = blockIdx.y, b = blockIdx.z;
    const _Float16* zb = z16 + (long)b * NP * K;
    const _Float16* mb = mu16 + ((long)b << 15) + (long)(ct * 64 + w * 16 + l15) * K + l4 * 8;
    f32x4 acc[4];
    #pragma unroll
    for (int pj = 0; pj < 4; ++pj) acc[pj] = (f32x4){0.f, 0.f, 0.f, 0.f};
    #pragma unroll
    for (int kc = 0; kc < 64; kc += 32) {
        f16x8 bfr = *(const f16x8*)(mb + kc);
        #pragma unroll
        for (int pj = 0; pj < 4; ++pj) {
            f16x8 a = *(const f16x8*)(zb + (long)(p0 + pj * 16 + l15) * K + kc + l4 * 8);
            acc[pj] = __builtin_amdgcn_mfma_f32_16x16x32_f16(a, bfr, acc[pj], 0, 0, 0);
        }
    }
    // row (A) = p_local = pj*16+l4*4+i, col (B) = c_local = w*16+l15
    #pragma unroll
    for (int pj = 0; pj < 4; ++pj)
        #pragma unroll
        for (int i = 0; i < 4; ++i)
            rt[(pj * 16 + l4 * 4 + i) * 80 + w * 16 + l15] = (_Float16)fmaxf(acc[pj][i], 0.f);
    __syncthreads();
    #pragma unroll
    for (int it = 0; it < 2; ++it) {
        int l = t + it * 256;
        int row = l >> 3, s8 = l & 7;
        *(s16x8*)&recT[((long)b * NP + p0 + row) * CH + ct * 64 + s8 * 8] =
            *(const s16x8*)&rt[row * 80 + s8 * 8];
    }
}

// ---------------- BN batch stats --------------------------------------------
__global__ __launch_bounds__(256) void bn_stats(const float* __restrict__ y2,
                                                float* __restrict__ stats,
                                                float* __restrict__ statsq)
{
    int d = blockIdx.x;
    int t = threadIdx.x;
    float s = 0.f, sq = 0.f;
    for (int idx = t; idx < BI * HW; idx += 256) {
        int bi = idx >> 10, hw = idx & 1023;
        float v = y2[(long)bi * CH * HW + (long)d * HW + hw];
        s += v; sq += v * v;
    }
    for (int off = 32; off; off >>= 1) {
        s += __shfl_xor(s, off, 64);
        sq += __shfl_xor(sq, off, 64);
    }
    __shared__ float ps[8];
    int wv = t >> 6, ln = t & 63;
    if (ln == 0) { ps[wv] = s; ps[4 + wv] = sq; }
    __syncthreads();
    if (t == 0) {
        stats[d]  = ps[0] + ps[1] + ps[2] + ps[3];
        statsq[d] = ps[4] + ps[5] + ps[6] + ps[7];
    }
}

// ---------------- finale: BN + residual + relu, plus mu_b copy --------------
__global__ __launch_bounds__(256) void final_kernel(
    const float* __restrict__ y2, const float* __restrict__ x,
    const float* __restrict__ stats, const float* __restrict__ statsq,
    const float* __restrict__ gamma, const float* __restrict__ beta,
    const float* __restrict__ mu_cur, float* __restrict__ out)
{
    long i = (long)blockIdx.x * 256 + threadIdx.x;
    const long NMAIN = (long)BI * CH * HW;
    if (i < NMAIN) {
        int d = (int)((i >> 10) & (CH - 1));
        float s = stats[d], sq = statsq[d];
        const float inv = 1.f / (float)(BI * HW);
        float mean = s * inv;
        float var = sq * inv - mean * mean;
        float rs = rsqrtf(var + 1e-5f);
        float v = (y2[i] - mean) * rs * gamma[d] + beta[d] + x[i];
        out[i] = fmaxf(v, 0.f);
    } else if (i < NMAIN + (long)BB * CH * K) {
        out[i] = mu_cur[i - NMAIN];
    }
}

extern "C" void kernel_launch(void* const* d_in, const int* in_sizes, int n_in,
                              void* d_out, int out_size, void* d_ws, size_t ws_size,
                              hipStream_t stream) {
    const float* x   = (const float*)d_in[0];
    const float* mu0 = (const float*)d_in[1];
    const float* w1  = (const float*)d_in[2];
    const float* b1  = (const float*)d_in[3];
    const float* w2  = (const float*)d_in[4];
    const float* gm  = (const float*)d_in[5];
    const float* bt  = (const float*)d_in[6];
    float* out = (float*)d_out;

    float* ws = (float*)d_ws;
    // fp16 regions (sizes in float-slots)
    _Float16* y16h  = (_Float16*)(ws);              // [8][512][5120]  10,485,760 f
    _Float16* yT16h = (_Float16*)(ws + 10485760);   // [8][5120][512]  (reused as recT)
    _Float16* xTh   = (_Float16*)(ws + 20971520);   // [40960][512]    10,485,760 f
    _Float16* zTh   = (_Float16*)(ws + 20971520);   // [8][64][5120]   1,310,720 f (reuses xT)
    _Float16* z16h  = (_Float16*)(ws + 22282240);   // [8][5120][64]   1,310,720 f
    float*    macc  = ws + 23592960;                // [8][8][64][512] 2,097,152 f
    float*    mu_cur = ws + 31457280;               // 262,144 f
    _Float16* Wh1   = (_Float16*)(ws + 31719424);   // 131,072 f
    _Float16* Wh2   = (_Float16*)(ws + 31850496);   // 131,072 f
    _Float16* mu16h = (_Float16*)(ws + 31981568);   // 131,072 f
    _Float16* muTh  = (_Float16*)(ws + 32112640);   // 131,072 f
    float*    zsum  = ws + 32243712;                // 512
    float*    stats = ws + 32244224;                // 512
    float*    statsq = ws + 32244736;               // 512
    float* y2 = out;

    wconv<<<1024, 256, 0, stream>>>(w1, Wh1);
    wconv<<<1024, 256, 0, stream>>>(w2, Wh2);
    transpose_f16<<<dim3(16, 8, 40), 256, 0, stream>>>(x, xTh, HW);
    conv_tile<<<dim3(8, 4, 40), 256, 0, stream>>>(Wh1, xTh, b1, nullptr, y16h, yT16h, 0);
    bcast_mu2<<<1024, 256, 0, stream>>>(mu0, mu_cur, muTh);

    for (int s = 0; s < 5; ++s) {
        hipMemsetAsync(zsum, 0, 512 * sizeof(float), stream);
        stage_z_mfma<<<dim3(80, 8), 256, 0, stream>>>(yT16h, muTh, zTh, z16h, zsum, s == 4);
        stage_mu_mfma<<<dim3(8, 8, 8), 256, 0, stream>>>(y16h, zTh, macc);
        mu_norm2<<<128, 256, 0, stream>>>(macc, zsum, mu_cur, mu16h, muTh);
    }

    // rec overwrites yT16 region (dead after last stage_z)
    rec_mfma<<<dim3(80, 8, 8), 256, 0, stream>>>(z16h, mu16h, yT16h);
    conv_tile<<<dim3(8, 4, 40), 256, 0, stream>>>(Wh2, yT16h, nullptr, y2, nullptr, nullptr, 1);
    bn_stats<<<512, 256, 0, stream>>>(y2, stats, statsq);
    long total = (long)BI * CH * HW + (long)BB * CH * K;
    final_kernel<<<(int)((total + 255) / 256), 256, 0, stream>>>(
        y2, x, stats, statsq, gm, bt, mu_cur, out);
}

// Round 7
// 464.704 us; speedup vs baseline: 3.7872x; 1.0608x over previous
//
#include <hip/hip_runtime.h>
#include <math.h>

#define CH 512
#define K 64
#define BB 8
#define NIMG 5
#define HW 1024
#define NP 5120   // NIMG*HW
#define BI 40     // BB*NIMG

typedef __attribute__((ext_vector_type(8))) _Float16 f16x8;
typedef __attribute__((ext_vector_type(4))) _Float16 f16x4;
typedef __attribute__((ext_vector_type(4))) float f32x4;
typedef __attribute__((ext_vector_type(8))) short s16x8;

#define AS1 __attribute__((address_space(1)))
#define AS3 __attribute__((address_space(3)))

// ---------------- W fp32 -> fp16 (row-major copy) ---------------------------
__global__ __launch_bounds__(256) void wconv(const float* __restrict__ w,
                                             _Float16* __restrict__ o)
{
    int i = blockIdx.x * 256 + threadIdx.x;   // 262144
    o[i] = (_Float16)w[i];
}

// ---------------- transpose fp32 [z][512][P] -> fp16 [z][P][512] ------------
__global__ __launch_bounds__(256) void transpose_f16(
    const float* __restrict__ in, _Float16* __restrict__ out, int P)
{
    __shared__ float tile[64][65];
    int t = threadIdx.x;
    int p0 = blockIdx.x * 64, c0 = blockIdx.y * 64;
    long ibase = (long)blockIdx.z * CH * P;
    long obase = (long)blockIdx.z * P * CH;
    int pl = t & 63, chh = t >> 6;
    #pragma unroll
    for (int i = 0; i < 16; ++i)
        tile[chh + i * 4][pl] = in[ibase + (long)(c0 + chh + i * 4) * P + p0 + pl];
    __syncthreads();
    int cc = t & 31, pr = t >> 5;
    #pragma unroll
    for (int i = 0; i < 8; ++i) {
        int p = pr + i * 8;
        _Float16 lo = (_Float16)tile[cc * 2][p];
        _Float16 hi = (_Float16)tile[cc * 2 + 1][p];
        unsigned lob = (unsigned)*(unsigned short*)&lo;
        unsigned hib = (unsigned)*(unsigned short*)&hi;
        *(unsigned*)&out[obase + (long)(p0 + p) * CH + c0 + cc * 2] = lob | (hib << 16);
    }
}

// ---------------- broadcast mu -> mu_cur fp32 + muT fp16 --------------------
__global__ __launch_bounds__(256) void bcast_mu2(const float* __restrict__ mu_in,
                                                 float* __restrict__ mu_cur,
                                                 _Float16* __restrict__ muT)
{
    int i = blockIdx.x * 256 + threadIdx.x;   // [b][c][k], 262144
    float v = mu_in[i & 32767];
    mu_cur[i] = v;
    int b = i >> 15, ck = i & 32767, c = ck >> 6, k = ck & 63;
    muT[((long)b << 15) + k * CH + c] = (_Float16)v;
}

// ---------------- conv via 2-phase tiled MFMA -------------------------------
// out[d,p] = sum_c W[d,c] * inT[p,c].  128d x 128p tile, BK=64, 4 waves,
// DOUBLE-buffered LDS; stage(next) issued BEFORE compute(cur); one barrier/step.
// Swizzle per rule #21: linear LDS dest, XOR-swizzled global src, swizzled read.
// mode 0 = conv1 (writes y16 + yT16, +bias); mode 1 = conv2 (y2 fp32 + BN stats).
__global__ __launch_bounds__(256) void conv_tile(
    const _Float16* __restrict__ Wh, const _Float16* __restrict__ inT,
    const float* __restrict__ bias, float* __restrict__ y2,
    _Float16* __restrict__ y16, _Float16* __restrict__ yT16,
    float* __restrict__ stats, float* __restrict__ statsq, int mode)
{
    __shared__ _Float16 Wt[2][128 * 64];   // 2 x 16 KB
    __shared__ _Float16 Xt[2][128 * 64];   // 2 x 16 KB
    int t = threadIdx.x;
    int lane = t & 63, w = t >> 6;
    int l15 = lane & 15, l4 = lane >> 4;
    int wd = w & 1, wp = w >> 1;        // wave quadrant: 64d x 64p
    int bi = blockIdx.z;
    int d0 = blockIdx.y * 128;
    int pl0 = blockIdx.x * 128;         // p within image
    long prow0 = (long)bi * HW + pl0;   // row in inT (valid for both modes)
    int ci_row = lane >> 3;             // sub-row within an 8-row gll call
    int colb_phys = (lane & 7) * 16;    // physical byte col this lane fills

    f32x4 acc[4][4];
    #pragma unroll
    for (int ai = 0; ai < 4; ++ai)
        #pragma unroll
        for (int bj = 0; bj < 4; ++bj) acc[ai][bj] = (f32x4){0.f, 0.f, 0.f, 0.f};

#define STAGE(buf, cc0)                                                          \
    {                                                                            \
        _Pragma("unroll")                                                        \
        for (int i = 0; i < 4; ++i) {                                            \
            int row = w * 32 + i * 8 + ci_row;                                   \
            int cb = colb_phys ^ ((row & 7) << 4);                               \
            const _Float16* srcW = Wh + (long)(d0 + row) * CH + (cc0) + (cb >> 1);\
            const _Float16* srcX = inT + (prow0 + row) * (long)CH + (cc0) + (cb >> 1);\
            __builtin_amdgcn_global_load_lds((const AS1 void*)srcW,              \
                (AS3 void*)&Wt[buf][(w * 32 + i * 8) * 64], 16, 0, 0);           \
            __builtin_amdgcn_global_load_lds((const AS1 void*)srcX,              \
                (AS3 void*)&Xt[buf][(w * 32 + i * 8) * 64], 16, 0, 0);           \
        }                                                                        \
    }

    STAGE(0, 0)
    __syncthreads();
    for (int c0 = 0; c0 < CH; c0 += 64) {
        int cur = (c0 >> 6) & 1;
        if (c0 + 64 < CH) STAGE(cur ^ 1, c0 + 64)
        #pragma unroll
        for (int kk = 0; kk < 2; ++kk) {
            f16x8 af[4], bf[4];
            #pragma unroll
            for (int ai = 0; ai < 4; ++ai) {
                int row = wd * 64 + ai * 16 + l15;
                int cb = (kk * 64 + l4 * 16) ^ ((row & 7) << 4);
                af[ai] = *(const f16x8*)((const char*)&Wt[cur][0] + row * 128 + cb);
            }
            #pragma unroll
            for (int bj = 0; bj < 4; ++bj) {
                int row = wp * 64 + bj * 16 + l15;
                int cb = (kk * 64 + l4 * 16) ^ ((row & 7) << 4);
                bf[bj] = *(const f16x8*)((const char*)&Xt[cur][0] + row * 128 + cb);
            }
            #pragma unroll
            for (int ai = 0; ai < 4; ++ai)
                #pragma unroll
                for (int bj = 0; bj < 4; ++bj)
                    acc[ai][bj] = __builtin_amdgcn_mfma_f32_16x16x32_f16(
                        af[ai], bf[bj], acc[ai][bj], 0, 0, 0);
        }
        __syncthreads();   // drains vmcnt(0): next tile landed; cur consumed
    }
#undef STAGE

    // C/D: col = l15 (p within 16-block), row = l4*4 + reg (d)
    int b = bi / NIMG, n = bi % NIMG;
    if (mode == 0) {
        #pragma unroll
        for (int ai = 0; ai < 4; ++ai) {
            int dd = d0 + wd * 64 + ai * 16 + l4 * 4;
            float b0 = bias[dd], b1 = bias[dd + 1], b2 = bias[dd + 2], b3 = bias[dd + 3];
            #pragma unroll
            for (int bj = 0; bj < 4; ++bj) {
                int pb = n * HW + pl0 + wp * 64 + bj * 16 + l15;
                f16x4 pk = { (_Float16)(acc[ai][bj][0] + b0), (_Float16)(acc[ai][bj][1] + b1),
                             (_Float16)(acc[ai][bj][2] + b2), (_Float16)(acc[ai][bj][3] + b3) };
                *(f16x4*)&yT16[((long)b * NP + pb) * CH + dd] = pk;
                long yb = ((long)b * CH + dd) * NP + pb;
                y16[yb] = pk[0];
                y16[yb + NP] = pk[1];
                y16[yb + 2 * NP] = pk[2];
                y16[yb + 3 * NP] = pk[3];
            }
        }
    } else {
        long obase = (long)bi * CH * HW;
        #pragma unroll
        for (int ai = 0; ai < 4; ++ai) {
            int dd = d0 + wd * 64 + ai * 16 + l4 * 4;
            #pragma unroll
            for (int bj = 0; bj < 4; ++bj) {
                int p = pl0 + wp * 64 + bj * 16 + l15;
                long o = obase + (long)dd * HW + p;
                y2[o] = acc[ai][bj][0];
                y2[o + HW] = acc[ai][bj][1];
                y2[o + 2 * HW] = acc[ai][bj][2];
                y2[o + 3 * HW] = acc[ai][bj][3];
            }
        }
        // fused BN batch stats: reduce over this wave's 64 p per d, atomicAdd
        #pragma unroll
        for (int ai = 0; ai < 4; ++ai) {
            #pragma unroll
            for (int i = 0; i < 4; ++i) {
                float s = acc[ai][0][i] + acc[ai][1][i] + acc[ai][2][i] + acc[ai][3][i];
                float q = acc[ai][0][i] * acc[ai][0][i] + acc[ai][1][i] * acc[ai][1][i]
                        + acc[ai][2][i] * acc[ai][2][i] + acc[ai][3][i] * acc[ai][3][i];
                #pragma unroll
                for (int off = 1; off < 16; off <<= 1) {
                    s += __shfl_xor(s, off, 64);
                    q += __shfl_xor(q, off, 64);
                }
                if (l15 == 0) {
                    int dd = d0 + wd * 64 + ai * 16 + l4 * 4 + i;
                    atomicAdd(&stats[dd], s);
                    atomicAdd(&statsq[dd], q);
                }
            }
        }
    }
}

// ---------------- EM: S=yT*muT (MFMA) + softmax + zT/z16/zsum ---------------
__global__ __launch_bounds__(256) void stage_z_mfma(
    const _Float16* __restrict__ yT, const _Float16* __restrict__ muT,
    _Float16* __restrict__ zT, _Float16* __restrict__ z16,
    float* __restrict__ zsum, int writeZ)
{
    __shared__ _Float16 ms[32768];   // frag-order muT: [chunk16][j4][lane64][8] = 64KB
    int t = threadIdx.x;
    int w = t >> 6, lane = t & 63, l15 = lane & 15, l4 = lane >> 4;
    int p0 = blockIdx.x * 64;
    int b = blockIdx.y;
    const _Float16* mb = muT + ((long)b << 15);
    #pragma unroll
    for (int it = 0; it < 16; ++it) {
        int sl = t + it * 256;
        int cc = sl >> 8, j = (sl >> 6) & 3, ln = sl & 63;
        int rl15 = ln & 15, rl4 = ln >> 4;
        *(s16x8*)&ms[sl * 8] = *(const s16x8*)&mb[(rl15 + 16 * j) * CH + cc * 32 + rl4 * 8];
    }
    const _Float16* arow = yT + ((long)b * NP + p0 + w * 16 + l15) * CH + l4 * 8;
    f32x4 acc[4];
    #pragma unroll
    for (int j = 0; j < 4; ++j) acc[j] = (f32x4){0.f, 0.f, 0.f, 0.f};
    __syncthreads();
    #pragma unroll
    for (int cc = 0; cc < 16; ++cc) {
        f16x8 a = *(const f16x8*)(arow + cc * 32);
        #pragma unroll
        for (int j = 0; j < 4; ++j) {
            f16x8 bj = *(const f16x8*)&ms[((cc * 4 + j) * 64 + lane) * 8];
            acc[j] = __builtin_amdgcn_mfma_f32_16x16x32_f16(a, bj, acc[j], 0, 0, 0);
        }
    }
    // lane holds S[p = p0+w*16+l4*4+i][k = l15+16j]; softmax over k per p-row.
    float zv[4][4];
    #pragma unroll
    for (int i = 0; i < 4; ++i) {
        float m = fmaxf(fmaxf(acc[0][i], acc[1][i]), fmaxf(acc[2][i], acc[3][i]));
        #pragma unroll
        for (int off = 1; off < 16; off <<= 1) m = fmaxf(m, __shfl_xor(m, off, 64));
        float e0 = __expf(acc[0][i] - m);
        float e1 = __expf(acc[1][i] - m);
        float e2 = __expf(acc[2][i] - m);
        float e3 = __expf(acc[3][i] - m);
        float s = e0 + e1 + e2 + e3;
        #pragma unroll
        for (int off = 1; off < 16; off <<= 1) s += __shfl_xor(s, off, 64);
        float inv = 1.f / s;
        zv[0][i] = e0 * inv; zv[1][i] = e1 * inv; zv[2][i] = e2 * inv; zv[3][i] = e3 * inv;
    }
    int prow = p0 + w * 16 + l4 * 4;
    long ztbase = (long)b * K * NP;
    #pragma unroll
    for (int j = 0; j < 4; ++j) {
        f16x4 pk = { (_Float16)zv[j][0], (_Float16)zv[j][1],
                     (_Float16)zv[j][2], (_Float16)zv[j][3] };
        *(f16x4*)&zT[ztbase + (long)(l15 + 16 * j) * NP + prow] = pk;
    }
    if (writeZ) {
        long zbase = (long)b * NP * K;
        #pragma unroll
        for (int j = 0; j < 4; ++j)
            #pragma unroll
            for (int i = 0; i < 4; ++i)
                z16[zbase + (long)(prow + i) * K + l15 + 16 * j] = (_Float16)zv[j][i];
    }
    float part[4];
    #pragma unroll
    for (int j = 0; j < 4; ++j) {
        part[j] = zv[j][0] + zv[j][1] + zv[j][2] + zv[j][3];
        part[j] += __shfl_xor(part[j], 16, 64);
        part[j] += __shfl_xor(part[j], 32, 64);
    }
    __syncthreads();                 // ms no longer needed -> reuse as zred
    float* zred = (float*)ms;
    if (l4 == 0) {
        #pragma unroll
        for (int j = 0; j < 4; ++j) zred[w * 64 + l15 + 16 * j] = part[j];
    }
    __syncthreads();
    if (t < 64)
        atomicAdd(&zsum[b * 64 + t], zred[t] + zred[64 + t] + zred[128 + t] + zred[192 + t]);
}

// ---------------- EM: macc[pc][b][k][c] = sum_p y16[c][p]*zT[k][p] ----------
__global__ __launch_bounds__(256) void stage_mu_mfma(
    const _Float16* __restrict__ y16, const _Float16* __restrict__ zT,
    float* __restrict__ macc)
{
    __shared__ _Float16 zs[4096];    // frag-order, 64-p chunk: 8KB
    int t = threadIdx.x;
    int w = t >> 6, lane = t & 63, l15 = lane & 15, l4 = lane >> 4;
    int pc = blockIdx.x, ct = blockIdx.y, b = blockIdx.z;
    int pbase = pc * 640;
    const _Float16* zsrc = zT + (long)b * K * NP + (long)(l15 + 16 * w) * NP + l4 * 8;
    const _Float16* arow = y16 + ((long)b * CH + ct * 64 + w * 16 + l15) * NP + l4 * 8;
    f32x4 acc[4];
    #pragma unroll
    for (int j = 0; j < 4; ++j) acc[j] = (f32x4){0.f, 0.f, 0.f, 0.f};
    for (int p0 = pbase; p0 < pbase + 640; p0 += 64) {
        __syncthreads();
        *(s16x8*)&zs[t * 8] = *(const s16x8*)(zsrc + p0);
        *(s16x8*)&zs[2048 + t * 8] = *(const s16x8*)(zsrc + p0 + 32);
        __syncthreads();
        f16x8 a0 = *(const f16x8*)(arow + p0);
        f16x8 a1 = *(const f16x8*)(arow + p0 + 32);
        #pragma unroll
        for (int j = 0; j < 4; ++j) {
            f16x8 bj0 = *(const f16x8*)&zs[(j * 64 + lane) * 8];
            acc[j] = __builtin_amdgcn_mfma_f32_16x16x32_f16(a0, bj0, acc[j], 0, 0, 0);
            f16x8 bj1 = *(const f16x8*)&zs[2048 + (j * 64 + lane) * 8];
            acc[j] = __builtin_amdgcn_mfma_f32_16x16x32_f16(a1, bj1, acc[j], 0, 0, 0);
        }
    }
    // output: row (A) = c = ct*64+w*16+l4*4+i, col (B) = k = l15+16j
    float* mp = macc + ((long)pc * BB + b) * K * CH;
    #pragma unroll
    for (int j = 0; j < 4; ++j)
        *(f32x4*)&mp[(long)(l15 + 16 * j) * CH + ct * 64 + w * 16 + l4 * 4] = acc[j];
}

// ---------------- mu normalize: sum partials, l2norm, emit 3 formats --------
__global__ __launch_bounds__(256) void mu_norm2(
    const float* __restrict__ macc, const float* __restrict__ zsum,
    float* __restrict__ mu_cur, _Float16* __restrict__ mu16,
    _Float16* __restrict__ muT)
{
    int gw = blockIdx.x * 4 + (threadIdx.x >> 6);   // 512 = 8b x 64k
    int lane = threadIdx.x & 63;
    int b = gw >> 6, k = gw & 63;
    float v[8];
    float s = 0.f;
    #pragma unroll
    for (int ci = 0; ci < 8; ++ci) {
        int c = ci * 64 + lane;
        float a = 0.f;
        #pragma unroll
        for (int pcc = 0; pcc < 8; ++pcc)
            a += macc[(((long)pcc * BB + b) * K + k) * CH + c];
        v[ci] = a; s += a * a;
    }
    #pragma unroll
    for (int off = 1; off < 64; off <<= 1) s += __shfl_xor(s, off, 64);
    float d = 1e-6f + zsum[b * 64 + k];
    float scale = 1.f / (1e-6f * d + sqrtf(s));
    long mb = (long)b << 15;
    #pragma unroll
    for (int ci = 0; ci < 8; ++ci) {
        int c = ci * 64 + lane;
        float m = v[ci] * scale;
        mu_cur[mb + (long)c * K + k] = m;
        mu16[mb + (long)c * K + k] = (_Float16)m;
        muT[mb + (long)k * CH + c] = (_Float16)m;
    }
}

// ---------------- rec: recT[p][c] = relu(sum_k z16[p][k]*mu16[c][k]) --------
__global__ __launch_bounds__(256) void rec_mfma(
    const _Float16* __restrict__ z16, const _Float16* __restrict__ mu16,
    _Float16* __restrict__ recT)
{
    __shared__ _Float16 rt[64 * 80];
    int t = threadIdx.x;
    int w = t >> 6, lane = t & 63, l15 = lane & 15, l4 = lane >> 4;
    int p0 = blockIdx.x * 64, ct = blockIdx.y, b = blockIdx.z;
    const _Float16* zb = z16 + (long)b * NP * K;
    const _Float16* mb = mu16 + ((long)b << 15) + (long)(ct * 64 + w * 16 + l15) * K + l4 * 8;
    f32x4 acc[4];
    #pragma unroll
    for (int pj = 0; pj < 4; ++pj) acc[pj] = (f32x4){0.f, 0.f, 0.f, 0.f};
    #pragma unroll
    for (int kc = 0; kc < 64; kc += 32) {
        f16x8 bfr = *(const f16x8*)(mb + kc);
        #pragma unroll
        for (int pj = 0; pj < 4; ++pj) {
            f16x8 a = *(const f16x8*)(zb + (long)(p0 + pj * 16 + l15) * K + kc + l4 * 8);
            acc[pj] = __builtin_amdgcn_mfma_f32_16x16x32_f16(a, bfr, acc[pj], 0, 0, 0);
        }
    }
    // row (A) = p_local = pj*16+l4*4+i, col (B) = c_local = w*16+l15
    #pragma unroll
    for (int pj = 0; pj < 4; ++pj)
        #pragma unroll
        for (int i = 0; i < 4; ++i)
            rt[(pj * 16 + l4 * 4 + i) * 80 + w * 16 + l15] = (_Float16)fmaxf(acc[pj][i], 0.f);
    __syncthreads();
    #pragma unroll
    for (int it = 0; it < 2; ++it) {
        int l = t + it * 256;
        int row = l >> 3, s8 = l & 7;
        *(s16x8*)&recT[((long)b * NP + p0 + row) * CH + ct * 64 + s8 * 8] =
            *(const s16x8*)&rt[row * 80 + s8 * 8];
    }
}

// ---------------- finale: BN + residual + relu, plus mu_b copy (float4) -----
__global__ __launch_bounds__(256) void final_kernel(
    const float* __restrict__ y2, const float* __restrict__ x,
    const float* __restrict__ stats, const float* __restrict__ statsq,
    const float* __restrict__ gamma, const float* __restrict__ beta,
    const float* __restrict__ mu_cur, float* __restrict__ out)
{
    long i4 = (long)blockIdx.x * 256 + threadIdx.x;
    const long NMAIN4 = (long)BI * CH * HW / 4;     // 5242880
    if (i4 < NMAIN4) {
        long i = i4 * 4;
        int d = (int)((i >> 10) & (CH - 1));        // 1024 consecutive share d
        float s = stats[d], sq = statsq[d];
        const float inv = 1.f / (float)(BI * HW);
        float mean = s * inv;
        float var = sq * inv - mean * mean;
        float rs = rsqrtf(var + 1e-5f);
        float g = rs * gamma[d];
        float bb = beta[d] - mean * g;
        float4 yv = *(const float4*)&y2[i];
        float4 xv = *(const float4*)&x[i];
        float4 ov;
        ov.x = fmaxf(yv.x * g + bb + xv.x, 0.f);
        ov.y = fmaxf(yv.y * g + bb + xv.y, 0.f);
        ov.z = fmaxf(yv.z * g + bb + xv.z, 0.f);
        ov.w = fmaxf(yv.w * g + bb + xv.w, 0.f);
        *(float4*)&out[i] = ov;
    } else {
        long j = (i4 - NMAIN4) * 4;                 // mu tail: 262144 elements
        *(float4*)&out[(long)BI * CH * HW + j] = *(const float4*)&mu_cur[j];
    }
}

extern "C" void kernel_launch(void* const* d_in, const int* in_sizes, int n_in,
                              void* d_out, int out_size, void* d_ws, size_t ws_size,
                              hipStream_t stream) {
    const float* x   = (const float*)d_in[0];
    const float* mu0 = (const float*)d_in[1];
    const float* w1  = (const float*)d_in[2];
    const float* b1  = (const float*)d_in[3];
    const float* w2  = (const float*)d_in[4];
    const float* gm  = (const float*)d_in[5];
    const float* bt  = (const float*)d_in[6];
    float* out = (float*)d_out;

    float* ws = (float*)d_ws;
    // fp16 regions (sizes in float-slots)
    _Float16* y16h  = (_Float16*)(ws);              // [8][512][5120]  10,485,760 f
    _Float16* yT16h = (_Float16*)(ws + 10485760);   // [8][5120][512]  (reused as recT)
    _Float16* xTh   = (_Float16*)(ws + 20971520);   // [40960][512]    10,485,760 f
    _Float16* zTh   = (_Float16*)(ws + 20971520);   // [8][64][5120]   1,310,720 f (reuses xT)
    _Float16* z16h  = (_Float16*)(ws + 22282240);   // [8][5120][64]   1,310,720 f
    float*    macc  = ws + 23592960;                // [8][8][64][512] 2,097,152 f
    float*    mu_cur = ws + 31457280;               // 262,144 f
    _Float16* Wh1   = (_Float16*)(ws + 31719424);   // 131,072 f
    _Float16* Wh2   = (_Float16*)(ws + 31850496);   // 131,072 f
    _Float16* mu16h = (_Float16*)(ws + 31981568);   // 131,072 f
    _Float16* muTh  = (_Float16*)(ws + 32112640);   // 131,072 f
    float*    zsum  = ws + 32243712;                // [5][512] = 2560
    float*    stats = ws + 32246272;                // 512
    float*    statsq = ws + 32246784;               // 512
    float* y2 = out;

    // one upfront memset for zsum[5] + stats + statsq (3584 floats)
    hipMemsetAsync(zsum, 0, 3584 * sizeof(float), stream);

    wconv<<<1024, 256, 0, stream>>>(w1, Wh1);
    wconv<<<1024, 256, 0, stream>>>(w2, Wh2);
    transpose_f16<<<dim3(16, 8, 40), 256, 0, stream>>>(x, xTh, HW);
    conv_tile<<<dim3(8, 4, 40), 256, 0, stream>>>(Wh1, xTh, b1, nullptr, y16h, yT16h,
                                                  nullptr, nullptr, 0);
    bcast_mu2<<<1024, 256, 0, stream>>>(mu0, mu_cur, muTh);

    for (int s = 0; s < 5; ++s) {
        stage_z_mfma<<<dim3(80, 8), 256, 0, stream>>>(yT16h, muTh, zTh, z16h,
                                                      zsum + s * 512, s == 4);
        stage_mu_mfma<<<dim3(8, 8, 8), 256, 0, stream>>>(y16h, zTh, macc);
        mu_norm2<<<128, 256, 0, stream>>>(macc, zsum + s * 512, mu_cur, mu16h, muTh);
    }

    // rec overwrites yT16 region (dead after last stage_z)
    rec_mfma<<<dim3(80, 8, 8), 256, 0, stream>>>(z16h, mu16h, yT16h);
    conv_tile<<<dim3(8, 4, 40), 256, 0, stream>>>(Wh2, yT16h, nullptr, y2, nullptr, nullptr,
                                                  stats, statsq, 1);
    long total4 = ((long)BI * CH * HW + (long)BB * CH * K) / 4;
    final_kernel<<<(int)((total4 + 255) / 256), 256, 0, stream>>>(
        y2, x, stats, statsq, gm, bt, mu_cur, out);
}